// Round 2
// baseline (1297.046 us; speedup 1.0000x reference)
//
#include <hip/hip_runtime.h>
#include <math.h>

// Problem constants (match reference setup_inputs)
constexpr int NN  = 50000;   // nodes
constexpr int NE  = 640000;  // edges
constexpr int DIN = 256;
constexpr int DE  = 64;
constexpr int H1  = 128;
constexpr int H2  = 64;

// ---- float <-> order-preserving uint encoding for atomicMax on floats ----
__device__ inline unsigned enc_f(float f) {
  unsigned u = __float_as_uint(f);
  return (u & 0x80000000u) ? ~u : (u | 0x80000000u);
}
__device__ inline float dec_f(unsigned u) {
  return __uint_as_float((u & 0x80000000u) ? (u ^ 0x80000000u) : ~u);
}

// ---- pack 4 weight matrices [K,C] into Wcat [K,4C]; biases into bcat[4C] ----
__global__ __launch_bounds__(256) void pack4_kernel(
    const float* __restrict__ W0, const float* __restrict__ W1,
    const float* __restrict__ W2, const float* __restrict__ W3,
    const float* __restrict__ b0, const float* __restrict__ b1,
    const float* __restrict__ b2, const float* __restrict__ b3,
    float* __restrict__ Wcat, float* __restrict__ bcat, int K, int C) {
  int total = K * 4 * C;
  for (int idx = blockIdx.x * blockDim.x + threadIdx.x; idx < total;
       idx += gridDim.x * blockDim.x) {
    int c = idx % (4 * C);
    int k = idx / (4 * C);
    int which = c / C, cc = c % C;
    const float* W = which == 0 ? W0 : which == 1 ? W1 : which == 2 ? W2 : W3;
    Wcat[idx] = W[k * C + cc];
    if (k == 0) {
      const float* b = which == 0 ? b0 : which == 1 ? b1 : which == 2 ? b2 : b3;
      bcat[c] = b[cc];
    }
  }
}

// ---- generic fp32 GEMM: C[M,Nn] = A[M,K] @ B[K,Nn] + bias  (Nn%64==0, K%16==0)
__global__ __launch_bounds__(256) void gemm_bias_kernel(
    const float* __restrict__ A, const float* __restrict__ B,
    const float* __restrict__ bias, float* __restrict__ C,
    int M, int Nn, int K) {
  __shared__ float As[16][64];  // [k][m] (transposed)
  __shared__ float Bs[16][64];  // [k][n]
  int tid = threadIdx.x;
  int tx = tid & 15, ty = tid >> 4;
  int row0 = blockIdx.y * 64, col0 = blockIdx.x * 64;
  int ar = tid >> 2, ac = (tid & 3) << 2;   // A tile: 64 rows x 16 k
  int br = tid >> 4, bc = (tid & 15) << 2;  // B tile: 16 k x 64 cols
  float acc[4][4] = {};
  for (int k0 = 0; k0 < K; k0 += 16) {
    float4 av = make_float4(0.f, 0.f, 0.f, 0.f);
    if (row0 + ar < M)
      av = *(const float4*)(A + (size_t)(row0 + ar) * K + k0 + ac);
    As[ac + 0][ar] = av.x; As[ac + 1][ar] = av.y;
    As[ac + 2][ar] = av.z; As[ac + 3][ar] = av.w;
    *(float4*)(&Bs[br][bc]) =
        *(const float4*)(B + (size_t)(k0 + br) * Nn + col0 + bc);
    __syncthreads();
#pragma unroll
    for (int kk = 0; kk < 16; ++kk) {
      float4 a4 = *(const float4*)(&As[kk][ty << 2]);
      float4 b4 = *(const float4*)(&Bs[kk][tx << 2]);
      float a[4] = {a4.x, a4.y, a4.z, a4.w};
      float b[4] = {b4.x, b4.y, b4.z, b4.w};
#pragma unroll
      for (int i = 0; i < 4; i++)
#pragma unroll
        for (int j = 0; j < 4; j++)
          acc[i][j] = fmaf(a[i], b[j], acc[i][j]);
    }
    __syncthreads();
  }
  int col = col0 + (tx << 2);
  float4 bv = make_float4(0.f, 0.f, 0.f, 0.f);
  if (bias) bv = *(const float4*)(bias + col);
#pragma unroll
  for (int i = 0; i < 4; i++) {
    int row = row0 + (ty << 2) + i;
    if (row < M) {
      float4 o;
      o.x = acc[i][0] + bv.x; o.y = acc[i][1] + bv.y;
      o.z = acc[i][2] + bv.z; o.w = acc[i][3] + bv.w;
      *(float4*)(C + (size_t)row * Nn + col) = o;
    }
  }
}

// ---- per-edge attention logit + segment max (wave per edge) ----
template <int C>
__global__ __launch_bounds__(256) void alpha_kernel(
    const float* __restrict__ P, const float* __restrict__ Ew,
    const int* __restrict__ src, const int* __restrict__ dst,
    float* __restrict__ alpha, unsigned* __restrict__ mx,
    float scale, int nE) {
  int w = blockIdx.x * 4 + (threadIdx.x >> 6);
  int lane = threadIdx.x & 63;
  if (w >= nE) return;
  int s = src[w], d = dst[w];
  const float* q = P + (size_t)d * (4 * C);
  const float* k = P + (size_t)s * (4 * C) + C;
  const float* e = Ew + (size_t)w * C;
  float sum = 0.f;
#pragma unroll
  for (int c = lane; c < C; c += 64) sum = fmaf(q[c], k[c] + e[c], sum);
#pragma unroll
  for (int off = 32; off > 0; off >>= 1) sum += __shfl_xor(sum, off);
  if (lane == 0) {
    float a = sum * scale;
    alpha[w] = a;
    atomicMax(&mx[d], enc_f(a));
  }
}

// ---- exp(alpha - max) + segment sum (thread per edge) ----
__global__ __launch_bounds__(256) void expsum_kernel(
    const float* __restrict__ alpha, const int* __restrict__ dst,
    const unsigned* __restrict__ mx, float* __restrict__ exv,
    float* __restrict__ denom, int nE) {
  int e = blockIdx.x * blockDim.x + threadIdx.x;
  if (e >= nE) return;
  int d = dst[e];
  float m = dec_f(mx[d]);
  float v = expf(alpha[e] - m);
  exv[e] = v;
  atomicAdd(&denom[d], v);
}

// ---- weighted message scatter-add (wave per edge) ----
template <int C>
__global__ __launch_bounds__(256) void msg_kernel(
    const float* __restrict__ P, const float* __restrict__ Ew,
    const int* __restrict__ src, const int* __restrict__ dst,
    const float* __restrict__ exv, const float* __restrict__ denom,
    float* __restrict__ agg, int nE) {
  int w = blockIdx.x * 4 + (threadIdx.x >> 6);
  int lane = threadIdx.x & 63;
  if (w >= nE) return;
  int s = src[w], d = dst[w];
  float a = exv[w] / (denom[d] + 1e-16f);
  const float* v = P + (size_t)s * (4 * C) + 2 * C;
  const float* e = Ew + (size_t)w * C;
#pragma unroll
  for (int c = lane; c < C; c += 64)
    atomicAdd(&agg[(size_t)d * C + c], a * (v[c] + e[c]));
}

// ---- h = relu(agg + skip_proj) ----
template <int C>
__global__ __launch_bounds__(256) void finish_kernel(
    const float* __restrict__ agg, const float* __restrict__ P,
    float* __restrict__ h, int n) {
  int idx = blockIdx.x * blockDim.x + threadIdx.x;
  if (idx >= n * C) return;
  int node = idx / C, c = idx % C;
  float val = agg[idx] + P[(size_t)node * (4 * C) + 3 * C + c];
  h[idx] = fmaxf(val, 0.f);
}

// ---- out[n] = h2[n] @ Wc + bc  (h2 already relu'd; wave per node) ----
__global__ __launch_bounds__(256) void classifier_kernel(
    const float* __restrict__ h2, const float* __restrict__ Wc,
    const float* __restrict__ bc, float* __restrict__ out, int n) {
  int w = blockIdx.x * 4 + (threadIdx.x >> 6);
  int lane = threadIdx.x & 63;
  if (w >= n) return;
  float v = h2[(size_t)w * 64 + lane] * Wc[lane];
#pragma unroll
  for (int off = 32; off > 0; off >>= 1) v += __shfl_xor(v, off);
  if (lane == 0) out[w] = v + bc[0];
}

extern "C" void kernel_launch(void* const* d_in, const int* in_sizes, int n_in,
                              void* d_out, int out_size, void* d_ws,
                              size_t ws_size, hipStream_t stream) {
  const float* x         = (const float*)d_in[0];
  const int*   ei        = (const int*)d_in[1];
  const float* edge_attr = (const float*)d_in[2];
  const float* Wq1 = (const float*)d_in[3];  const float* bq1 = (const float*)d_in[4];
  const float* Wk1 = (const float*)d_in[5];  const float* bk1 = (const float*)d_in[6];
  const float* Wv1 = (const float*)d_in[7];  const float* bv1 = (const float*)d_in[8];
  const float* We1 = (const float*)d_in[9];
  const float* Ws1 = (const float*)d_in[10]; const float* bs1 = (const float*)d_in[11];
  const float* Wq2 = (const float*)d_in[12]; const float* bq2 = (const float*)d_in[13];
  const float* Wk2 = (const float*)d_in[14]; const float* bk2 = (const float*)d_in[15];
  const float* Wv2 = (const float*)d_in[16]; const float* bv2 = (const float*)d_in[17];
  const float* We2 = (const float*)d_in[18];
  const float* Ws2 = (const float*)d_in[19]; const float* bs2 = (const float*)d_in[20];
  const float* Wc  = (const float*)d_in[21]; const float* bc  = (const float*)d_in[22];
  float* out = (float*)d_out;

  const int* srcI = ei;        // edge_index[0]
  const int* dstI = ei + NE;   // edge_index[1]

  // ---- workspace layout (floats) ----
  char* ws = (char*)d_ws;
  size_t off = 0;
  auto alloc = [&](size_t nf) {
    float* p = (float*)(ws + off);
    off += nf * sizeof(float);
    return p;
  };
  float* W1cat = alloc((size_t)DIN * 4 * H1);   // [256,512]
  float* b1cat = alloc(4 * H1);
  float* W2cat = alloc((size_t)H1 * 4 * H2);    // [128,256]
  float* b2cat = alloc(4 * H2);
  float* P     = alloc((size_t)NN * 4 * H1);    // projections (layer1: [N,512]; layer2 reuses)
  float* Ew    = alloc((size_t)NE * H1);        // edge embeddings (layer1: [E,128]; layer2 reuses)
  float* alpha = alloc(NE);
  float* exv   = alloc(NE);
  unsigned* mx = (unsigned*)alloc(NN);
  float* denom = alloc(NN);
  float* agg   = alloc((size_t)NN * H1);
  float* h1    = alloc((size_t)NN * H1);
  float* h2    = alloc((size_t)NN * H2);
  (void)ws_size; (void)in_sizes; (void)n_in; (void)out_size;

  // ---- pack weights ----
  pack4_kernel<<<256, 256, 0, stream>>>(Wq1, Wk1, Wv1, Ws1, bq1, bk1, bv1, bs1,
                                        W1cat, b1cat, DIN, H1);
  pack4_kernel<<<256, 256, 0, stream>>>(Wq2, Wk2, Wv2, Ws2, bq2, bk2, bv2, bs2,
                                        W2cat, b2cat, H1, H2);

  // ================= Layer 1 (C = H1 = 128) =================
  {
    const int C = H1;
    // P1 = x @ W1cat + b1cat   [N, 512]
    gemm_bias_kernel<<<dim3(4 * C / 64, (NN + 63) / 64), 256, 0, stream>>>(
        x, W1cat, b1cat, P, NN, 4 * C, DIN);
    // Ew = edge_attr @ We1     [E, 128]
    gemm_bias_kernel<<<dim3(C / 64, (NE + 63) / 64), 256, 0, stream>>>(
        edge_attr, We1, nullptr, Ew, NE, C, DE);
    hipMemsetAsync(mx, 0, NN * sizeof(unsigned), stream);
    hipMemsetAsync(denom, 0, NN * sizeof(float), stream);
    hipMemsetAsync(agg, 0, (size_t)NN * C * sizeof(float), stream);
    alpha_kernel<H1><<<(NE + 3) / 4, 256, 0, stream>>>(
        P, Ew, srcI, dstI, alpha, mx, 0.08838834764831845f /*1/sqrt(128)*/, NE);
    expsum_kernel<<<(NE + 255) / 256, 256, 0, stream>>>(alpha, dstI, mx, exv,
                                                        denom, NE);
    msg_kernel<H1><<<(NE + 3) / 4, 256, 0, stream>>>(P, Ew, srcI, dstI, exv,
                                                     denom, agg, NE);
    finish_kernel<H1><<<((size_t)NN * C + 255) / 256, 256, 0, stream>>>(agg, P,
                                                                        h1, NN);
  }

  // ================= Layer 2 (C = H2 = 64) =================
  {
    const int C = H2;
    // P2 = h1 @ W2cat + b2cat   [N, 256]
    gemm_bias_kernel<<<dim3(4 * C / 64, (NN + 63) / 64), 256, 0, stream>>>(
        h1, W2cat, b2cat, P, NN, 4 * C, H1);
    // Ew = edge_attr @ We2      [E, 64]
    gemm_bias_kernel<<<dim3(C / 64, (NE + 63) / 64), 256, 0, stream>>>(
        edge_attr, We2, nullptr, Ew, NE, C, DE);
    hipMemsetAsync(mx, 0, NN * sizeof(unsigned), stream);
    hipMemsetAsync(denom, 0, NN * sizeof(float), stream);
    hipMemsetAsync(agg, 0, (size_t)NN * C * sizeof(float), stream);
    alpha_kernel<H2><<<(NE + 3) / 4, 256, 0, stream>>>(
        P, Ew, srcI, dstI, alpha, mx, 0.125f /*1/sqrt(64)*/, NE);
    expsum_kernel<<<(NE + 255) / 256, 256, 0, stream>>>(alpha, dstI, mx, exv,
                                                        denom, NE);
    msg_kernel<H2><<<(NE + 3) / 4, 256, 0, stream>>>(P, Ew, srcI, dstI, exv,
                                                     denom, agg, NE);
    finish_kernel<H2><<<((size_t)NN * C + 255) / 256, 256, 0, stream>>>(agg, P,
                                                                        h2, NN);
  }

  // ================= Classifier =================
  classifier_kernel<<<(NN + 3) / 4, 256, 0, stream>>>(h2, Wc, bc, out, NN);
}

// Round 3
// 875.843 us; speedup vs baseline: 1.4809x; 1.4809x over previous
//
#include <hip/hip_runtime.h>
#include <math.h>

// Problem constants (match reference setup_inputs)
constexpr int NN  = 50000;   // nodes
constexpr int NE  = 640000;  // edges
constexpr int DIN = 256;
constexpr int DE  = 64;
constexpr int H1  = 128;
constexpr int H2  = 64;

// ---- pack 4 weight matrices [K,C] into Wcat [K,4C]; biases into bcat[4C] ----
__global__ __launch_bounds__(256) void pack4_kernel(
    const float* __restrict__ W0, const float* __restrict__ W1,
    const float* __restrict__ W2, const float* __restrict__ W3,
    const float* __restrict__ b0, const float* __restrict__ b1,
    const float* __restrict__ b2, const float* __restrict__ b3,
    float* __restrict__ Wcat, float* __restrict__ bcat, int K, int C) {
  int total = K * 4 * C;
  for (int idx = blockIdx.x * blockDim.x + threadIdx.x; idx < total;
       idx += gridDim.x * blockDim.x) {
    int c = idx % (4 * C);
    int k = idx / (4 * C);
    int which = c / C, cc = c % C;
    const float* W = which == 0 ? W0 : which == 1 ? W1 : which == 2 ? W2 : W3;
    Wcat[idx] = W[k * C + cc];
    if (k == 0) {
      const float* b = which == 0 ? b0 : which == 1 ? b1 : which == 2 ? b2 : b3;
      bcat[c] = b[cc];
    }
  }
}

// ---- CSR build ----
__global__ __launch_bounds__(256) void hist_kernel(const int* __restrict__ dst,
                                                   int* __restrict__ deg, int nE) {
  int e = blockIdx.x * blockDim.x + threadIdx.x;
  if (e < nE) atomicAdd(&deg[dst[e]], 1);
}

// per-chunk(256) inclusive scan; part = inclusive-within-chunk, chunkSums = totals
__global__ __launch_bounds__(256) void scan1_kernel(const int* __restrict__ deg,
                                                    int* __restrict__ part,
                                                    int* __restrict__ chunkSums,
                                                    int n) {
  __shared__ int s[256];
  int tid = threadIdx.x;
  int i = blockIdx.x * 256 + tid;
  int v0 = (i < n) ? deg[i] : 0;
  s[tid] = v0;
  __syncthreads();
  for (int off = 1; off < 256; off <<= 1) {
    int v = (tid >= off) ? s[tid - off] : 0;
    __syncthreads();
    s[tid] += v;
    __syncthreads();
  }
  if (i < n) part[i] = s[tid];
  if (tid == 255) chunkSums[blockIdx.x] = s[255];
}

// single block: inclusive scan of chunkSums (nchunks <= 256)
__global__ __launch_bounds__(256) void scan2_kernel(int* __restrict__ chunkSums,
                                                    int nchunks) {
  __shared__ int s[256];
  int tid = threadIdx.x;
  s[tid] = (tid < nchunks) ? chunkSums[tid] : 0;
  __syncthreads();
  for (int off = 1; off < 256; off <<= 1) {
    int v = (tid >= off) ? s[tid - off] : 0;
    __syncthreads();
    s[tid] += v;
    __syncthreads();
  }
  if (tid < nchunks) chunkSums[tid] = s[tid];
}

__global__ __launch_bounds__(256) void scan3_kernel(const int* __restrict__ deg,
                                                    const int* __restrict__ part,
                                                    const int* __restrict__ chunkSums,
                                                    int* __restrict__ row_start,
                                                    int n, int nE) {
  int i = blockIdx.x * 256 + threadIdx.x;
  if (i < n)
    row_start[i] = part[i] - deg[i] + (blockIdx.x ? chunkSums[blockIdx.x - 1] : 0);
  if (i == 0) row_start[n] = nE;
}

__global__ __launch_bounds__(256) void scatter_kernel(const int* __restrict__ dst,
                                                      const int* __restrict__ row_start,
                                                      int* __restrict__ cursor,
                                                      int* __restrict__ eid, int nE) {
  int e = blockIdx.x * blockDim.x + threadIdx.x;
  if (e >= nE) return;
  int d = dst[e];
  int pos = row_start[d] + atomicAdd(&cursor[d], 1);
  eid[pos] = e;
}

// deterministic order: per-node insertion sort of edge ids; also extract src_csr
__global__ __launch_bounds__(256) void sort_extract_kernel(
    int* __restrict__ eid, const int* __restrict__ row_start,
    const int* __restrict__ srcI, int* __restrict__ src_csr, int n) {
  int v = blockIdx.x * blockDim.x + threadIdx.x;
  if (v >= n) return;
  int b = row_start[v], e = row_start[v + 1];
  for (int i = b + 1; i < e; i++) {
    int key = eid[i];
    int j = i - 1;
    while (j >= b && eid[j] > key) { eid[j + 1] = eid[j]; j--; }
    eid[j + 1] = key;
  }
  for (int i = b; i < e; i++) src_csr[i] = srcI[eid[i]];
}

// ---- generic fp32 GEMM: C[M,Nn] = A[M,K] @ B[K,Nn] + bias  (Nn%64==0, K%16==0)
// optional ridx: gather A rows (A[ridx[m]] instead of A[m])
__global__ __launch_bounds__(256) void gemm_bias_kernel(
    const float* __restrict__ A, const int* __restrict__ ridx,
    const float* __restrict__ B, const float* __restrict__ bias,
    float* __restrict__ C, int M, int Nn, int K) {
  __shared__ float As[16][64];  // [k][m] (transposed)
  __shared__ float Bs[16][64];  // [k][n]
  int tid = threadIdx.x;
  int tx = tid & 15, ty = tid >> 4;
  int row0 = blockIdx.y * 64, col0 = blockIdx.x * 64;
  int ar = tid >> 2, ac = (tid & 3) << 2;   // A tile: 64 rows x 16 k
  int br = tid >> 4, bc = (tid & 15) << 2;  // B tile: 16 k x 64 cols
  int arow = row0 + ar;
  size_t asrc = (arow < M) ? (size_t)(ridx ? ridx[arow] : arow) : 0;
  float acc[4][4] = {};
  for (int k0 = 0; k0 < K; k0 += 16) {
    float4 av = make_float4(0.f, 0.f, 0.f, 0.f);
    if (arow < M) av = *(const float4*)(A + asrc * K + k0 + ac);
    As[ac + 0][ar] = av.x; As[ac + 1][ar] = av.y;
    As[ac + 2][ar] = av.z; As[ac + 3][ar] = av.w;
    *(float4*)(&Bs[br][bc]) =
        *(const float4*)(B + (size_t)(k0 + br) * Nn + col0 + bc);
    __syncthreads();
#pragma unroll
    for (int kk = 0; kk < 16; ++kk) {
      float4 a4 = *(const float4*)(&As[kk][ty << 2]);
      float4 b4 = *(const float4*)(&Bs[kk][tx << 2]);
      float a[4] = {a4.x, a4.y, a4.z, a4.w};
      float b[4] = {b4.x, b4.y, b4.z, b4.w};
#pragma unroll
      for (int i = 0; i < 4; i++)
#pragma unroll
        for (int j = 0; j < 4; j++)
          acc[i][j] = fmaf(a[i], b[j], acc[i][j]);
    }
    __syncthreads();
  }
  int col = col0 + (tx << 2);
  float4 bv = make_float4(0.f, 0.f, 0.f, 0.f);
  if (bias) bv = *(const float4*)(bias + col);
#pragma unroll
  for (int i = 0; i < 4; i++) {
    int row = row0 + (ty << 2) + i;
    if (row < M) {
      float4 o;
      o.x = acc[i][0] + bv.x; o.y = acc[i][1] + bv.y;
      o.z = acc[i][2] + bv.z; o.w = acc[i][3] + bv.w;
      *(float4*)(C + (size_t)row * Nn + col) = o;
    }
  }
}

// ---- fused edge pass: online softmax + message agg + skip + relu ----
// wave per dst node. P[n] = [q | k | v | skip] (4C). Ew in CSR edge order.
template <int C>
__global__ __launch_bounds__(256) void fused_edge_kernel(
    const float* __restrict__ P, const float* __restrict__ Ew,
    const int* __restrict__ row_start, const int* __restrict__ src_csr,
    float* __restrict__ h, float scale, int n) {
  constexpr int CPL = C / 64;  // channels per lane (2 for C=128, 1 for C=64)
  int node = blockIdx.x * 4 + (threadIdx.x >> 6);
  int lane = threadIdx.x & 63;
  if (node >= n) return;
  const float* Pn = P + (size_t)node * (4 * C);
  int ch = lane * CPL;
  float q[CPL], acc[CPL], skip[CPL];
#pragma unroll
  for (int j = 0; j < CPL; j++) {
    q[j] = Pn[ch + j];
    skip[j] = Pn[3 * C + ch + j];
    acc[j] = 0.f;
  }
  float m = -INFINITY, denom = 0.f;
  int b = row_start[node], e = row_start[node + 1];
  for (int i = b; i < e; i++) {
    int s = src_csr[i];
    const float* Ps = P + (size_t)s * (4 * C);
    const float* Ee = Ew + (size_t)i * C;
    float kv[CPL], vv[CPL];
    float part = 0.f;
#pragma unroll
    for (int j = 0; j < CPL; j++) {
      float ev = Ee[ch + j];
      kv[j] = Ps[C + ch + j] + ev;
      vv[j] = Ps[2 * C + ch + j] + ev;
      part = fmaf(q[j], kv[j], part);
    }
#pragma unroll
    for (int off = 32; off > 0; off >>= 1) part += __shfl_xor(part, off);
    float logit = part * scale;
    float nm = fmaxf(m, logit);
    float f = expf(m - nm);      // 0 on first edge (m = -inf)
    float w = expf(logit - nm);
    denom = denom * f + w;
#pragma unroll
    for (int j = 0; j < CPL; j++) acc[j] = acc[j] * f + w * vv[j];
    m = nm;
  }
  float inv = 1.f / (denom + 1e-16f);
#pragma unroll
  for (int j = 0; j < CPL; j++)
    h[(size_t)node * C + ch + j] = fmaxf(acc[j] * inv + skip[j], 0.f);
}

// ---- out[n] = h2[n] @ Wc + bc  (wave per node) ----
__global__ __launch_bounds__(256) void classifier_kernel(
    const float* __restrict__ h2, const float* __restrict__ Wc,
    const float* __restrict__ bc, float* __restrict__ out, int n) {
  int w = blockIdx.x * 4 + (threadIdx.x >> 6);
  int lane = threadIdx.x & 63;
  if (w >= n) return;
  float v = h2[(size_t)w * 64 + lane] * Wc[lane];
#pragma unroll
  for (int off = 32; off > 0; off >>= 1) v += __shfl_xor(v, off);
  if (lane == 0) out[w] = v + bc[0];
}

extern "C" void kernel_launch(void* const* d_in, const int* in_sizes, int n_in,
                              void* d_out, int out_size, void* d_ws,
                              size_t ws_size, hipStream_t stream) {
  const float* x         = (const float*)d_in[0];
  const int*   ei        = (const int*)d_in[1];
  const float* edge_attr = (const float*)d_in[2];
  const float* Wq1 = (const float*)d_in[3];  const float* bq1 = (const float*)d_in[4];
  const float* Wk1 = (const float*)d_in[5];  const float* bk1 = (const float*)d_in[6];
  const float* Wv1 = (const float*)d_in[7];  const float* bv1 = (const float*)d_in[8];
  const float* We1 = (const float*)d_in[9];
  const float* Ws1 = (const float*)d_in[10]; const float* bs1 = (const float*)d_in[11];
  const float* Wq2 = (const float*)d_in[12]; const float* bq2 = (const float*)d_in[13];
  const float* Wk2 = (const float*)d_in[14]; const float* bk2 = (const float*)d_in[15];
  const float* Wv2 = (const float*)d_in[16]; const float* bv2 = (const float*)d_in[17];
  const float* We2 = (const float*)d_in[18];
  const float* Ws2 = (const float*)d_in[19]; const float* bs2 = (const float*)d_in[20];
  const float* Wc  = (const float*)d_in[21]; const float* bc  = (const float*)d_in[22];
  float* out = (float*)d_out;

  const int* srcI = ei;        // edge_index[0]
  const int* dstI = ei + NE;   // edge_index[1]

  // ---- workspace layout ----
  char* ws = (char*)d_ws;
  size_t off = 0;
  auto allocf = [&](size_t nf) {
    float* p = (float*)(ws + off);
    off += nf * sizeof(float);
    return p;
  };
  auto alloci = [&](size_t ni) {
    int* p = (int*)(ws + off);
    off += ni * sizeof(int);
    return p;
  };
  float* W1cat = allocf((size_t)DIN * 4 * H1);   // [256,512]
  float* b1cat = allocf(4 * H1);
  float* W2cat = allocf((size_t)H1 * 4 * H2);    // [128,256]
  float* b2cat = allocf(4 * H2);
  float* P     = allocf((size_t)NN * 4 * H1);    // [N,512] L1 / [N,256] L2 (reused)
  float* Ew    = allocf((size_t)NE * H1);        // CSR-ordered edge emb (L1 128 / L2 64)
  float* h1    = allocf((size_t)NN * H1);
  float* h2    = allocf((size_t)NN * H2);
  int* deg       = alloci(NN);
  int* cursor    = alloci(NN);
  int* row_start = alloci(NN + 1);
  int* part      = alloci(((NN + 255) / 256) * 256);
  int* chunkSums = alloci(256);
  int* eid       = alloci(NE);
  int* src_csr   = alloci(NE);
  (void)ws_size; (void)in_sizes; (void)n_in; (void)out_size;

  const int nchunks = (NN + 255) / 256;  // 196 (<= 256)

  // ---- pack weights ----
  pack4_kernel<<<256, 256, 0, stream>>>(Wq1, Wk1, Wv1, Ws1, bq1, bk1, bv1, bs1,
                                        W1cat, b1cat, DIN, H1);
  pack4_kernel<<<256, 256, 0, stream>>>(Wq2, Wk2, Wv2, Ws2, bq2, bk2, bv2, bs2,
                                        W2cat, b2cat, H1, H2);

  // ---- CSR build (sort edges by dst; deterministic within-node order) ----
  hipMemsetAsync(deg, 0, NN * sizeof(int), stream);
  hipMemsetAsync(cursor, 0, NN * sizeof(int), stream);
  hist_kernel<<<(NE + 255) / 256, 256, 0, stream>>>(dstI, deg, NE);
  scan1_kernel<<<nchunks, 256, 0, stream>>>(deg, part, chunkSums, NN);
  scan2_kernel<<<1, 256, 0, stream>>>(chunkSums, nchunks);
  scan3_kernel<<<nchunks, 256, 0, stream>>>(deg, part, chunkSums, row_start, NN, NE);
  scatter_kernel<<<(NE + 255) / 256, 256, 0, stream>>>(dstI, row_start, cursor,
                                                       eid, NE);
  sort_extract_kernel<<<(NN + 255) / 256, 256, 0, stream>>>(eid, row_start, srcI,
                                                            src_csr, NN);

  // ================= Layer 1 (C = H1 = 128) =================
  {
    const int C = H1;
    gemm_bias_kernel<<<dim3(4 * C / 64, (NN + 63) / 64), 256, 0, stream>>>(
        x, nullptr, W1cat, b1cat, P, NN, 4 * C, DIN);
    // Ew_csr = edge_attr[eid] @ We1   [E,128] in CSR order
    gemm_bias_kernel<<<dim3(C / 64, (NE + 63) / 64), 256, 0, stream>>>(
        edge_attr, eid, We1, nullptr, Ew, NE, C, DE);
    fused_edge_kernel<H1><<<(NN + 3) / 4, 256, 0, stream>>>(
        P, Ew, row_start, src_csr, h1, 0.08838834764831845f, NN);
  }

  // ================= Layer 2 (C = H2 = 64) =================
  {
    const int C = H2;
    gemm_bias_kernel<<<dim3(4 * C / 64, (NN + 63) / 64), 256, 0, stream>>>(
        h1, nullptr, W2cat, b2cat, P, NN, 4 * C, H1);
    gemm_bias_kernel<<<dim3(C / 64, (NE + 63) / 64), 256, 0, stream>>>(
        edge_attr, eid, We2, nullptr, Ew, NE, C, DE);
    fused_edge_kernel<H2><<<(NN + 3) / 4, 256, 0, stream>>>(
        P, Ew, row_start, src_csr, h2, 0.125f, NN);
  }

  // ================= Classifier =================
  classifier_kernel<<<(NN + 3) / 4, 256, 0, stream>>>(h2, Wc, bc, out, NN);
}

// Round 5
// 814.142 us; speedup vs baseline: 1.5931x; 1.0758x over previous
//
#include <hip/hip_runtime.h>
#include <math.h>

// Problem constants (match reference setup_inputs)
constexpr int NN  = 50000;   // nodes
constexpr int NE  = 640000;  // edges
constexpr int DIN = 256;
constexpr int DE  = 64;
constexpr int H1  = 128;
constexpr int H2  = 64;

using u16 = unsigned short;
typedef __attribute__((ext_vector_type(8))) short bf16x8;
typedef __attribute__((ext_vector_type(4))) float f32x4;

// ---- fp32 -> bf16 (RTN) and back ----
__device__ inline u16 f2bf(float f) {
  unsigned u = __float_as_uint(f);
  unsigned r = (u + 0x7FFFu + ((u >> 16) & 1u)) >> 16;
  return (u16)r;
}
__device__ inline float bf2f(u16 h) { return __uint_as_float(((unsigned)h) << 16); }
__device__ inline unsigned pack2(u16 a, u16 b) {
  return (unsigned)a | ((unsigned)b << 16);
}
__device__ inline f32x4 mfma16(bf16x8 a, bf16x8 b, f32x4 c) {
  return __builtin_amdgcn_mfma_f32_16x16x32_bf16(a, b, c, 0, 0, 0);
}

// ---- pack nmats weight matrices W[K,C] into transposed split Bt[n][k] (n = which*C+cc)
__global__ __launch_bounds__(256) void packwt_kernel(
    const float* __restrict__ W0, const float* __restrict__ W1,
    const float* __restrict__ W2, const float* __restrict__ W3,
    const float* __restrict__ b0, const float* __restrict__ b1,
    const float* __restrict__ b2, const float* __restrict__ b3,
    u16* __restrict__ Bth, u16* __restrict__ Btl, float* __restrict__ bcat,
    int K, int C, int nmats) {
  int total = nmats * C * K;
  for (int idx = blockIdx.x * blockDim.x + threadIdx.x; idx < total;
       idx += gridDim.x * blockDim.x) {
    int k = idx % K;
    int n = idx / K;             // n = which*C + cc
    int which = n / C, cc = n % C;
    const float* W = which == 0 ? W0 : which == 1 ? W1 : which == 2 ? W2 : W3;
    float v = W[k * C + cc];
    u16 h = f2bf(v);
    Bth[(size_t)n * K + k] = h;
    Btl[(size_t)n * K + k] = f2bf(v - bf2f(h));
    if (k == 0 && bcat) {
      const float* b = which == 0 ? b0 : which == 1 ? b1 : which == 2 ? b2 : b3;
      bcat[n] = b ? b[cc] : 0.f;
    }
  }
}

// ---- CSR build ----
__global__ __launch_bounds__(256) void hist_kernel(const int* __restrict__ dst,
                                                   int* __restrict__ deg, int nE) {
  int e = blockIdx.x * blockDim.x + threadIdx.x;
  if (e < nE) atomicAdd(&deg[dst[e]], 1);
}

__global__ __launch_bounds__(256) void scan1_kernel(const int* __restrict__ deg,
                                                    int* __restrict__ part,
                                                    int* __restrict__ chunkSums,
                                                    int n) {
  __shared__ int s[256];
  int tid = threadIdx.x;
  int i = blockIdx.x * 256 + tid;
  int v0 = (i < n) ? deg[i] : 0;
  s[tid] = v0;
  __syncthreads();
  for (int off = 1; off < 256; off <<= 1) {
    int v = (tid >= off) ? s[tid - off] : 0;
    __syncthreads();
    s[tid] += v;
    __syncthreads();
  }
  if (i < n) part[i] = s[tid];
  if (tid == 255) chunkSums[blockIdx.x] = s[255];
}

__global__ __launch_bounds__(256) void scan2_kernel(int* __restrict__ chunkSums,
                                                    int nchunks) {
  __shared__ int s[256];
  int tid = threadIdx.x;
  s[tid] = (tid < nchunks) ? chunkSums[tid] : 0;
  __syncthreads();
  for (int off = 1; off < 256; off <<= 1) {
    int v = (tid >= off) ? s[tid - off] : 0;
    __syncthreads();
    s[tid] += v;
    __syncthreads();
  }
  if (tid < nchunks) chunkSums[tid] = s[tid];
}

__global__ __launch_bounds__(256) void scan3_kernel(const int* __restrict__ deg,
                                                    const int* __restrict__ part,
                                                    const int* __restrict__ chunkSums,
                                                    int* __restrict__ row_start,
                                                    int n, int nE) {
  int i = blockIdx.x * 256 + threadIdx.x;
  if (i < n)
    row_start[i] = part[i] - deg[i] + (blockIdx.x ? chunkSums[blockIdx.x - 1] : 0);
  if (i == 0) row_start[n] = nE;
}

__global__ __launch_bounds__(256) void scatter_kernel(const int* __restrict__ dst,
                                                      const int* __restrict__ row_start,
                                                      int* __restrict__ cursor,
                                                      int* __restrict__ eid, int nE) {
  int e = blockIdx.x * blockDim.x + threadIdx.x;
  if (e >= nE) return;
  int d = dst[e];
  int pos = row_start[d] + atomicAdd(&cursor[d], 1);
  eid[pos] = e;
}

__global__ __launch_bounds__(256) void sort_extract_kernel(
    int* __restrict__ eid, const int* __restrict__ row_start,
    const int* __restrict__ srcI, int* __restrict__ src_csr, int n) {
  int v = blockIdx.x * blockDim.x + threadIdx.x;
  if (v >= n) return;
  int b = row_start[v], e = row_start[v + 1];
  for (int i = b + 1; i < e; i++) {
    int key = eid[i];
    int j = i - 1;
    while (j >= b && eid[j] > key) { eid[j + 1] = eid[j]; j--; }
    eid[j + 1] = key;
  }
  for (int i = b; i < e; i++) src_csr[i] = srcI[eid[i]];
}

// ---- split-bf16 MFMA GEMM: Cout[M,Nn] = A[M,K](f32, optional row-gather) @ Bt^T + bias
// Bt is pre-transposed split weights [Nn][K] (bf16 hi/lo). Nn % BN == 0, K % 32 == 0.
// 3-product Markidis split: err ~2^-15 relative (fp32-quality for this tolerance).
template <int BN>
__global__ __launch_bounds__(256) void mfma_gemm_kernel(
    const float* __restrict__ A, const int* __restrict__ ridx,
    const u16* __restrict__ Bth, const u16* __restrict__ Btl,
    const float* __restrict__ bias, float* __restrict__ Cout,
    int M, int Nn, int K) {
  constexpr int BM = 128, BK = 32;
  constexpr int NI = BN / 32;  // 16-col frags per wave (wave covers BN/2)
  __shared__ __align__(16) u16 Ah[BM * BK], Al[BM * BK];
  __shared__ __align__(16) u16 Bh[BN * BK], Bl[BN * BK];
  int tid = threadIdx.x;
  int lane = tid & 63, wid = tid >> 6;
  int wm = wid >> 1, wn = wid & 1;
  int row0 = blockIdx.y * BM, col0 = blockIdx.x * BN;
  int k8 = lane >> 4, rb = lane & 15;

  f32x4 acc[4][NI];
#pragma unroll
  for (int mi = 0; mi < 4; mi++)
#pragma unroll
    for (int ni = 0; ni < NI; ni++) acc[mi][ni] = (f32x4){0.f, 0.f, 0.f, 0.f};

  // A staging assignments: 2 chunks (8 f32 each) per thread
  size_t aoff[2];
  int sdst[2];
  for (int p = 0; p < 2; p++) {
    int idx = p * 256 + tid;
    int r = idx >> 2, c = idx & 3;
    int ar = row0 + r;
    if (ar >= M) ar = M - 1;
    if (ridx) ar = ridx[ar];
    aoff[p] = (size_t)ar * K + c * 8;
    sdst[p] = r * BK + ((c ^ ((r >> 1) & 3)) << 3);  // chunk-XOR swizzle
  }

  for (int k0 = 0; k0 < K; k0 += BK) {
    __syncthreads();
    // stage A: read f32, split to bf16 hi/lo
#pragma unroll
    for (int p = 0; p < 2; p++) {
      const float* s = A + aoff[p] + k0;
      float4 u = *(const float4*)s, v = *(const float4*)(s + 4);
      float f[8] = {u.x, u.y, u.z, u.w, v.x, v.y, v.z, v.w};
      u16 h[8], l[8];
#pragma unroll
      for (int j = 0; j < 8; j++) {
        h[j] = f2bf(f[j]);
        l[j] = f2bf(f[j] - bf2f(h[j]));
      }
      *(uint4*)&Ah[sdst[p]] = make_uint4(pack2(h[0], h[1]), pack2(h[2], h[3]),
                                         pack2(h[4], h[5]), pack2(h[6], h[7]));
      *(uint4*)&Al[sdst[p]] = make_uint4(pack2(l[0], l[1]), pack2(l[2], l[3]),
                                         pack2(l[4], l[5]), pack2(l[6], l[7]));
    }
    // stage B (already bf16 split, [Nn][K] row-major)
#pragma unroll
    for (int p = 0; p < (BN * 4) / 256; p++) {
      int idx = p * 256 + tid;
      int n = idx >> 2, c = idx & 3;
      size_t goff = (size_t)(col0 + n) * K + k0 + c * 8;  // FIX: global col = col0 + n
      int doff = n * BK + ((c ^ ((n >> 1) & 3)) << 3);
      *(uint4*)&Bh[doff] = *(const uint4*)&Bth[goff];
      *(uint4*)&Bl[doff] = *(const uint4*)&Btl[goff];
    }
    __syncthreads();
    // fragments
    bf16x8 ah[4], al[4], bh[NI], bl[NI];
#pragma unroll
    for (int mi = 0; mi < 4; mi++) {
      int row = wm * 64 + mi * 16 + rb;
      int off = row * BK + ((k8 ^ ((row >> 1) & 3)) << 3);
      ah[mi] = *(const bf16x8*)&Ah[off];
      al[mi] = *(const bf16x8*)&Al[off];
    }
#pragma unroll
    for (int ni = 0; ni < NI; ni++) {
      int cn = wn * (BN / 2) + ni * 16 + rb;
      int off = cn * BK + ((k8 ^ ((cn >> 1) & 3)) << 3);
      bh[ni] = *(const bf16x8*)&Bh[off];
      bl[ni] = *(const bf16x8*)&Bl[off];
    }
#pragma unroll
    for (int mi = 0; mi < 4; mi++)
#pragma unroll
      for (int ni = 0; ni < NI; ni++) {
        f32x4 c = acc[mi][ni];
        c = mfma16(ah[mi], bh[ni], c);
        c = mfma16(al[mi], bh[ni], c);
        c = mfma16(ah[mi], bl[ni], c);
        acc[mi][ni] = c;
      }
  }
  // epilogue: D layout col=lane&15, row=(lane>>4)*4+reg (m89-verified)
#pragma unroll
  for (int ni = 0; ni < NI; ni++) {
    int col = col0 + wn * (BN / 2) + ni * 16 + rb;
    float bv = bias ? bias[col] : 0.f;
#pragma unroll
    for (int mi = 0; mi < 4; mi++) {
#pragma unroll
      for (int q = 0; q < 4; q++) {
        int row = row0 + wm * 64 + mi * 16 + k8 * 4 + q;
        if (row < M) Cout[(size_t)row * Nn + col] = acc[mi][ni][q] + bv;
      }
    }
  }
}

// ---- fused edge pass: online softmax + message agg + skip + relu ----
// wave per dst node. P[n] = [q | k | v | skip] (4C). Ew in CSR edge order.
template <int C>
__global__ __launch_bounds__(256) void fused_edge_kernel(
    const float* __restrict__ P, const float* __restrict__ Ew,
    const int* __restrict__ row_start, const int* __restrict__ src_csr,
    float* __restrict__ h, float scale, int n) {
  constexpr int CPL = C / 64;  // channels per lane
  int node = blockIdx.x * 4 + (threadIdx.x >> 6);
  int lane = threadIdx.x & 63;
  if (node >= n) return;
  const float* Pn = P + (size_t)node * (4 * C);
  int ch = lane * CPL;
  float q[CPL], acc[CPL], skip[CPL];
#pragma unroll
  for (int j = 0; j < CPL; j++) {
    q[j] = Pn[ch + j];
    skip[j] = Pn[3 * C + ch + j];
    acc[j] = 0.f;
  }
  float m = -INFINITY, denom = 0.f;
  int b = row_start[node], e = row_start[node + 1];
  for (int i = b; i < e; i++) {
    int s = src_csr[i];
    const float* Ps = P + (size_t)s * (4 * C);
    const float* Ee = Ew + (size_t)i * C;
    float kv[CPL], vv[CPL];
    float part = 0.f;
#pragma unroll
    for (int j = 0; j < CPL; j++) {
      float ev = Ee[ch + j];
      kv[j] = Ps[C + ch + j] + ev;
      vv[j] = Ps[2 * C + ch + j] + ev;
      part = fmaf(q[j], kv[j], part);
    }
#pragma unroll
    for (int off = 32; off > 0; off >>= 1) part += __shfl_xor(part, off);
    float logit = part * scale;
    float nm = fmaxf(m, logit);
    float f = expf(m - nm);
    float w = expf(logit - nm);
    denom = denom * f + w;
#pragma unroll
    for (int j = 0; j < CPL; j++) acc[j] = acc[j] * f + w * vv[j];
    m = nm;
  }
  float inv = 1.f / (denom + 1e-16f);
#pragma unroll
  for (int j = 0; j < CPL; j++)
    h[(size_t)node * C + ch + j] = fmaxf(acc[j] * inv + skip[j], 0.f);
}

// ---- out[n] = h2[n] @ Wc + bc  (wave per node) ----
__global__ __launch_bounds__(256) void classifier_kernel(
    const float* __restrict__ h2, const float* __restrict__ Wc,
    const float* __restrict__ bc, float* __restrict__ out, int n) {
  int w = blockIdx.x * 4 + (threadIdx.x >> 6);
  int lane = threadIdx.x & 63;
  if (w >= n) return;
  float v = h2[(size_t)w * 64 + lane] * Wc[lane];
#pragma unroll
  for (int off = 32; off > 0; off >>= 1) v += __shfl_xor(v, off);
  if (lane == 0) out[w] = v + bc[0];
}

extern "C" void kernel_launch(void* const* d_in, const int* in_sizes, int n_in,
                              void* d_out, int out_size, void* d_ws,
                              size_t ws_size, hipStream_t stream) {
  const float* x         = (const float*)d_in[0];
  const int*   ei        = (const int*)d_in[1];
  const float* edge_attr = (const float*)d_in[2];
  const float* Wq1 = (const float*)d_in[3];  const float* bq1 = (const float*)d_in[4];
  const float* Wk1 = (const float*)d_in[5];  const float* bk1 = (const float*)d_in[6];
  const float* Wv1 = (const float*)d_in[7];  const float* bv1 = (const float*)d_in[8];
  const float* We1 = (const float*)d_in[9];
  const float* Ws1 = (const float*)d_in[10]; const float* bs1 = (const float*)d_in[11];
  const float* Wq2 = (const float*)d_in[12]; const float* bq2 = (const float*)d_in[13];
  const float* Wk2 = (const float*)d_in[14]; const float* bk2 = (const float*)d_in[15];
  const float* Wv2 = (const float*)d_in[16]; const float* bv2 = (const float*)d_in[17];
  const float* We2 = (const float*)d_in[18];
  const float* Ws2 = (const float*)d_in[19]; const float* bs2 = (const float*)d_in[20];
  const float* Wc  = (const float*)d_in[21]; const float* bc  = (const float*)d_in[22];
  float* out = (float*)d_out;

  const int* srcI = ei;        // edge_index[0]
  const int* dstI = ei + NE;   // edge_index[1]

  // ---- workspace layout (256B-aligned slices) ----
  char* ws = (char*)d_ws;
  size_t off = 0;
  auto alloc = [&](size_t bytes) {
    void* p = ws + off;
    off += (bytes + 255) & ~(size_t)255;
    return p;
  };
  float* P     = (float*)alloc((size_t)NN * 4 * H1 * 4);   // [N,512] L1 / [N,256] L2
  float* Ew    = (float*)alloc((size_t)NE * H1 * 4);       // CSR-ordered edge emb
  float* h1    = (float*)alloc((size_t)NN * H1 * 4);
  float* h2    = (float*)alloc((size_t)NN * H2 * 4);
  u16* B1h = (u16*)alloc((size_t)4 * H1 * DIN * 2);
  u16* B1l = (u16*)alloc((size_t)4 * H1 * DIN * 2);
  u16* E1h = (u16*)alloc((size_t)H1 * DE * 2);
  u16* E1l = (u16*)alloc((size_t)H1 * DE * 2);
  u16* B2h = (u16*)alloc((size_t)4 * H2 * H1 * 2);
  u16* B2l = (u16*)alloc((size_t)4 * H2 * H1 * 2);
  u16* E2h = (u16*)alloc((size_t)H2 * DE * 2);
  u16* E2l = (u16*)alloc((size_t)H2 * DE * 2);
  float* b1cat = (float*)alloc(4 * H1 * 4);
  float* b2cat = (float*)alloc(4 * H2 * 4);
  int* deg       = (int*)alloc(NN * 4);
  int* cursor    = (int*)alloc(NN * 4);
  int* row_start = (int*)alloc((NN + 1) * 4);
  int* part      = (int*)alloc(((NN + 255) / 256) * 256 * 4);
  int* chunkSums = (int*)alloc(256 * 4);
  int* eid       = (int*)alloc(NE * 4);
  int* src_csr   = (int*)alloc(NE * 4);
  (void)ws_size; (void)in_sizes; (void)n_in; (void)out_size;

  const int nchunks = (NN + 255) / 256;  // 196 (<= 256)

  // ---- pack weights (transpose + bf16 split) ----
  packwt_kernel<<<256, 256, 0, stream>>>(Wq1, Wk1, Wv1, Ws1, bq1, bk1, bv1, bs1,
                                         B1h, B1l, b1cat, DIN, H1, 4);
  packwt_kernel<<<64, 256, 0, stream>>>(We1, nullptr, nullptr, nullptr, nullptr,
                                        nullptr, nullptr, nullptr, E1h, E1l,
                                        nullptr, DE, H1, 1);
  packwt_kernel<<<128, 256, 0, stream>>>(Wq2, Wk2, Wv2, Ws2, bq2, bk2, bv2, bs2,
                                         B2h, B2l, b2cat, H1, H2, 4);
  packwt_kernel<<<16, 256, 0, stream>>>(We2, nullptr, nullptr, nullptr, nullptr,
                                        nullptr, nullptr, nullptr, E2h, E2l,
                                        nullptr, DE, H2, 1);

  // ---- CSR build (sort edges by dst; deterministic within-node order) ----
  hipMemsetAsync(deg, 0, NN * sizeof(int), stream);
  hipMemsetAsync(cursor, 0, NN * sizeof(int), stream);
  hist_kernel<<<(NE + 255) / 256, 256, 0, stream>>>(dstI, deg, NE);
  scan1_kernel<<<nchunks, 256, 0, stream>>>(deg, part, chunkSums, NN);
  scan2_kernel<<<1, 256, 0, stream>>>(chunkSums, nchunks);
  scan3_kernel<<<nchunks, 256, 0, stream>>>(deg, part, chunkSums, row_start, NN, NE);
  scatter_kernel<<<(NE + 255) / 256, 256, 0, stream>>>(dstI, row_start, cursor,
                                                       eid, NE);
  sort_extract_kernel<<<(NN + 255) / 256, 256, 0, stream>>>(eid, row_start, srcI,
                                                            src_csr, NN);

  // ================= Layer 1 (C = H1 = 128) =================
  mfma_gemm_kernel<128><<<dim3(4 * H1 / 128, (NN + 127) / 128), 256, 0, stream>>>(
      x, nullptr, B1h, B1l, b1cat, P, NN, 4 * H1, DIN);
  mfma_gemm_kernel<128><<<dim3(H1 / 128, NE / 128), 256, 0, stream>>>(
      edge_attr, eid, E1h, E1l, nullptr, Ew, NE, H1, DE);
  fused_edge_kernel<H1><<<(NN + 3) / 4, 256, 0, stream>>>(
      P, Ew, row_start, src_csr, h1, 0.08838834764831845f, NN);

  // ================= Layer 2 (C = H2 = 64) =================
  mfma_gemm_kernel<128><<<dim3(4 * H2 / 128, (NN + 127) / 128), 256, 0, stream>>>(
      h1, nullptr, B2h, B2l, b2cat, P, NN, 4 * H2, H1);
  mfma_gemm_kernel<64><<<dim3(H2 / 64, NE / 128), 256, 0, stream>>>(
      edge_attr, eid, E2h, E2l, nullptr, Ew, NE, H2, DE);
  fused_edge_kernel<H2><<<(NN + 3) / 4, 256, 0, stream>>>(
      P, Ew, row_start, src_csr, h2, 0.125f, NN);

  // ================= Classifier =================
  classifier_kernel<<<(NN + 3) / 4, 256, 0, stream>>>(h2, Wc, bc, out, NN);
}

// Round 6
// 648.550 us; speedup vs baseline: 1.9999x; 1.2553x over previous
//
#include <hip/hip_runtime.h>
#include <math.h>

// Problem constants (match reference setup_inputs)
constexpr int NN  = 50000;   // nodes
constexpr int NE  = 640000;  // edges
constexpr int DIN = 256;
constexpr int DE  = 64;
constexpr int H1  = 128;
constexpr int H2  = 64;
constexpr int EWS = H1 + H2; // 192: combined edge-emb row stride

using u16 = unsigned short;
typedef __attribute__((ext_vector_type(8))) short bf16x8;
typedef __attribute__((ext_vector_type(4))) float f32x4;

// ---- fp32 -> bf16 (RTN) and back ----
__device__ inline u16 f2bf(float f) {
  unsigned u = __float_as_uint(f);
  unsigned r = (u + 0x7FFFu + ((u >> 16) & 1u)) >> 16;
  return (u16)r;
}
__device__ inline float bf2f(u16 h) { return __uint_as_float(((unsigned)h) << 16); }
__device__ inline unsigned pack2(u16 a, u16 b) {
  return (unsigned)a | ((unsigned)b << 16);
}
__device__ inline f32x4 mfma16(bf16x8 a, bf16x8 b, f32x4 c) {
  return __builtin_amdgcn_mfma_f32_16x16x32_bf16(a, b, c, 0, 0, 0);
}

// ---- pack nmats weight matrices W[K,C] into transposed split Bt[n][k] (n = which*C+cc)
__global__ __launch_bounds__(256) void packwt_kernel(
    const float* __restrict__ W0, const float* __restrict__ W1,
    const float* __restrict__ W2, const float* __restrict__ W3,
    const float* __restrict__ b0, const float* __restrict__ b1,
    const float* __restrict__ b2, const float* __restrict__ b3,
    u16* __restrict__ Bth, u16* __restrict__ Btl, float* __restrict__ bcat,
    int K, int C, int nmats) {
  int total = nmats * C * K;
  for (int idx = blockIdx.x * blockDim.x + threadIdx.x; idx < total;
       idx += gridDim.x * blockDim.x) {
    int k = idx % K;
    int n = idx / K;             // n = which*C + cc
    int which = n / C, cc = n % C;
    const float* W = which == 0 ? W0 : which == 1 ? W1 : which == 2 ? W2 : W3;
    float v = W[k * C + cc];
    u16 h = f2bf(v);
    Bth[(size_t)n * K + k] = h;
    Btl[(size_t)n * K + k] = f2bf(v - bf2f(h));
    if (k == 0 && bcat) {
      const float* b = which == 0 ? b0 : which == 1 ? b1 : which == 2 ? b2 : b3;
      bcat[n] = b ? b[cc] : 0.f;
    }
  }
}

// ---- CSR build ----
__global__ __launch_bounds__(256) void hist_kernel(const int* __restrict__ dst,
                                                   int* __restrict__ deg, int nE) {
  int e = blockIdx.x * blockDim.x + threadIdx.x;
  if (e < nE) atomicAdd(&deg[dst[e]], 1);
}

__global__ __launch_bounds__(256) void scan1_kernel(const int* __restrict__ deg,
                                                    int* __restrict__ part,
                                                    int* __restrict__ chunkSums,
                                                    int n) {
  __shared__ int s[256];
  int tid = threadIdx.x;
  int i = blockIdx.x * 256 + tid;
  int v0 = (i < n) ? deg[i] : 0;
  s[tid] = v0;
  __syncthreads();
  for (int off = 1; off < 256; off <<= 1) {
    int v = (tid >= off) ? s[tid - off] : 0;
    __syncthreads();
    s[tid] += v;
    __syncthreads();
  }
  if (i < n) part[i] = s[tid];
  if (tid == 255) chunkSums[blockIdx.x] = s[255];
}

__global__ __launch_bounds__(256) void scan2_kernel(int* __restrict__ chunkSums,
                                                    int nchunks) {
  __shared__ int s[256];
  int tid = threadIdx.x;
  s[tid] = (tid < nchunks) ? chunkSums[tid] : 0;
  __syncthreads();
  for (int off = 1; off < 256; off <<= 1) {
    int v = (tid >= off) ? s[tid - off] : 0;
    __syncthreads();
    s[tid] += v;
    __syncthreads();
  }
  if (tid < nchunks) chunkSums[tid] = s[tid];
}

__global__ __launch_bounds__(256) void scan3_kernel(const int* __restrict__ deg,
                                                    const int* __restrict__ part,
                                                    const int* __restrict__ chunkSums,
                                                    int* __restrict__ row_start,
                                                    int n, int nE) {
  int i = blockIdx.x * 256 + threadIdx.x;
  if (i < n)
    row_start[i] = part[i] - deg[i] + (blockIdx.x ? chunkSums[blockIdx.x - 1] : 0);
  if (i == 0) row_start[n] = nE;
}

__global__ __launch_bounds__(256) void scatter_kernel(const int* __restrict__ dst,
                                                      const int* __restrict__ row_start,
                                                      int* __restrict__ cursor,
                                                      int* __restrict__ eid, int nE) {
  int e = blockIdx.x * blockDim.x + threadIdx.x;
  if (e >= nE) return;
  int d = dst[e];
  int pos = row_start[d] + atomicAdd(&cursor[d], 1);
  eid[pos] = e;
}

__global__ __launch_bounds__(256) void sort_extract_kernel(
    int* __restrict__ eid, const int* __restrict__ row_start,
    const int* __restrict__ srcI, int* __restrict__ src_csr, int n) {
  int v = blockIdx.x * blockDim.x + threadIdx.x;
  if (v >= n) return;
  int b = row_start[v], e = row_start[v + 1];
  for (int i = b + 1; i < e; i++) {
    int key = eid[i];
    int j = i - 1;
    while (j >= b && eid[j] > key) { eid[j + 1] = eid[j]; j--; }
    eid[j + 1] = key;
  }
  for (int i = b; i < e; i++) src_csr[i] = srcI[eid[i]];
}

// ---- split-bf16 MFMA GEMM: Cout[M,Nn] = A[M,K](f32, optional row-gather) @ Bt^T + bias
// Bt is pre-transposed split weights [Nn][K] (bf16 hi/lo). Nn % BN == 0, K % 32 == 0.
// OBF16: output stored as bf16 (u16) via LDS-staged coalesced dwordx4 writes.
template <int BN, bool OBF16>
__global__ __launch_bounds__(256) void mfma_gemm_kernel(
    const float* __restrict__ A, const int* __restrict__ ridx,
    const u16* __restrict__ Bth, const u16* __restrict__ Btl,
    const float* __restrict__ bias, float* __restrict__ Cout,
    int M, int Nn, int K) {
  constexpr int BM = 128, BK = 32;
  constexpr int NI = BN / 32;  // 16-col frags per wave (wave covers BN/2)
  __shared__ __align__(16) u16 smem[(BM + BN) * BK * 2];
  u16* Ah = smem;
  u16* Al = smem + BM * BK;
  u16* Bh = smem + 2 * BM * BK;
  u16* Bl = smem + 2 * BM * BK + BN * BK;
  int tid = threadIdx.x;
  int lane = tid & 63, wid = tid >> 6;
  int wm = wid >> 1, wn = wid & 1;
  int row0 = blockIdx.y * BM, col0 = blockIdx.x * BN;
  int k8 = lane >> 4, rb = lane & 15;

  f32x4 acc[4][NI];
#pragma unroll
  for (int mi = 0; mi < 4; mi++)
#pragma unroll
    for (int ni = 0; ni < NI; ni++) acc[mi][ni] = (f32x4){0.f, 0.f, 0.f, 0.f};

  // A staging assignments: 2 chunks (8 f32 each) per thread
  size_t aoff[2];
  int sdst[2];
  for (int p = 0; p < 2; p++) {
    int idx = p * 256 + tid;
    int r = idx >> 2, c = idx & 3;
    int ar = row0 + r;
    if (ar >= M) ar = M - 1;
    if (ridx) ar = ridx[ar];
    aoff[p] = (size_t)ar * K + c * 8;
    sdst[p] = r * BK + ((c ^ ((r >> 1) & 3)) << 3);  // chunk-XOR swizzle
  }

  for (int k0 = 0; k0 < K; k0 += BK) {
    __syncthreads();
    // stage A: read f32, split to bf16 hi/lo
#pragma unroll
    for (int p = 0; p < 2; p++) {
      const float* s = A + aoff[p] + k0;
      float4 u = *(const float4*)s, v = *(const float4*)(s + 4);
      float f[8] = {u.x, u.y, u.z, u.w, v.x, v.y, v.z, v.w};
      u16 h[8], l[8];
#pragma unroll
      for (int j = 0; j < 8; j++) {
        h[j] = f2bf(f[j]);
        l[j] = f2bf(f[j] - bf2f(h[j]));
      }
      *(uint4*)&Ah[sdst[p]] = make_uint4(pack2(h[0], h[1]), pack2(h[2], h[3]),
                                         pack2(h[4], h[5]), pack2(h[6], h[7]));
      *(uint4*)&Al[sdst[p]] = make_uint4(pack2(l[0], l[1]), pack2(l[2], l[3]),
                                         pack2(l[4], l[5]), pack2(l[6], l[7]));
    }
    // stage B (already bf16 split, [Nn][K] row-major)
#pragma unroll
    for (int p = 0; p < (BN * 4) / 256; p++) {
      int idx = p * 256 + tid;
      int n = idx >> 2, c = idx & 3;
      size_t goff = (size_t)(col0 + n) * K + k0 + c * 8;
      int doff = n * BK + ((c ^ ((n >> 1) & 3)) << 3);
      *(uint4*)&Bh[doff] = *(const uint4*)&Bth[goff];
      *(uint4*)&Bl[doff] = *(const uint4*)&Btl[goff];
    }
    __syncthreads();
    // fragments
    bf16x8 ah[4], al[4], bh[NI], bl[NI];
#pragma unroll
    for (int mi = 0; mi < 4; mi++) {
      int row = wm * 64 + mi * 16 + rb;
      int off = row * BK + ((k8 ^ ((row >> 1) & 3)) << 3);
      ah[mi] = *(const bf16x8*)&Ah[off];
      al[mi] = *(const bf16x8*)&Al[off];
    }
#pragma unroll
    for (int ni = 0; ni < NI; ni++) {
      int cn = wn * (BN / 2) + ni * 16 + rb;
      int off = cn * BK + ((k8 ^ ((cn >> 1) & 3)) << 3);
      bh[ni] = *(const bf16x8*)&Bh[off];
      bl[ni] = *(const bf16x8*)&Bl[off];
    }
#pragma unroll
    for (int mi = 0; mi < 4; mi++)
#pragma unroll
      for (int ni = 0; ni < NI; ni++) {
        f32x4 c = acc[mi][ni];
        c = mfma16(ah[mi], bh[ni], c);
        c = mfma16(al[mi], bh[ni], c);
        c = mfma16(ah[mi], bl[ni], c);
        acc[mi][ni] = c;
      }
  }
  // epilogue: D layout col=lane&15, row=(lane>>4)*4+reg (m89-verified)
  if constexpr (OBF16) {
    // stage bf16 tile in LDS (XOR-swizzled), then coalesced dwordx4 writes
    u16* Cbf = (u16*)Cout;
    __syncthreads();
    u16* S = smem;  // [BM][BN] u16, needs BM*BN <= (BM+BN)*BK*2
#pragma unroll
    for (int ni = 0; ni < NI; ni++) {
      int coll = wn * (BN / 2) + ni * 16 + rb;
#pragma unroll
      for (int mi = 0; mi < 4; mi++) {
#pragma unroll
        for (int q = 0; q < 4; q++) {
          int rowl = wm * 64 + mi * 16 + k8 * 4 + q;
          S[rowl * BN + (coll ^ (((rowl >> 2) & 3) << 4))] = f2bf(acc[mi][ni][q]);
        }
      }
    }
    __syncthreads();
    constexpr int PASSES = (BM * BN * 2) / (256 * 16);
#pragma unroll
    for (int p = 0; p < PASSES; p++) {
      int idx = p * 256 + tid;      // uint4 index
      int r = idx / (BN / 8);
      int cp = idx % (BN / 8);
      int row = row0 + r;
      int cps = cp ^ (((r >> 2) & 3) << 1);  // inverse of the <<4 u16 swizzle
      if (row < M)
        *(uint4*)&Cbf[(size_t)row * Nn + col0 + cp * 8] =
            *(const uint4*)&S[r * BN + cps * 8];
    }
  } else {
#pragma unroll
    for (int ni = 0; ni < NI; ni++) {
      int col = col0 + wn * (BN / 2) + ni * 16 + rb;
      float bv = bias ? bias[col] : 0.f;
#pragma unroll
      for (int mi = 0; mi < 4; mi++) {
#pragma unroll
        for (int q = 0; q < 4; q++) {
          int row = row0 + wm * 64 + mi * 16 + k8 * 4 + q;
          if (row < M) Cout[(size_t)row * Nn + col] = acc[mi][ni][q] + bv;
        }
      }
    }
  }
}

// ---- fused edge pass: online softmax + message agg + skip + relu ----
// wave per dst node. P[n] = [q | k | v | skip] (4C). Ew bf16 [E][EWS], cols EOFF..EOFF+C.
template <int C, int EOFF>
__global__ __launch_bounds__(256) void fused_edge_kernel(
    const float* __restrict__ P, const u16* __restrict__ Ew,
    const int* __restrict__ row_start, const int* __restrict__ src_csr,
    float* __restrict__ h, float scale, int n) {
  constexpr int CPL = C / 64;  // channels per lane
  int node = blockIdx.x * 4 + (threadIdx.x >> 6);
  int lane = threadIdx.x & 63;
  if (node >= n) return;
  const float* Pn = P + (size_t)node * (4 * C);
  int ch = lane * CPL;
  float q[CPL], acc[CPL], skip[CPL];
#pragma unroll
  for (int j = 0; j < CPL; j++) {
    q[j] = Pn[ch + j];
    skip[j] = Pn[3 * C + ch + j];
    acc[j] = 0.f;
  }
  float m = -INFINITY, denom = 0.f;
  int b = row_start[node], e = row_start[node + 1];
  for (int i = b; i < e; i++) {
    int s = src_csr[i];
    const float* Ps = P + (size_t)s * (4 * C);
    const u16* Ee = Ew + (size_t)i * EWS + EOFF;
    float ev[CPL];
    if constexpr (CPL == 2) {
      unsigned u = *(const unsigned*)(Ee + ch);
      ev[0] = bf2f((u16)u);
      ev[1] = bf2f((u16)(u >> 16));
    } else {
      ev[0] = bf2f(Ee[ch]);
    }
    float kv[CPL], vv[CPL];
    float part = 0.f;
#pragma unroll
    for (int j = 0; j < CPL; j++) {
      kv[j] = Ps[C + ch + j] + ev[j];
      vv[j] = Ps[2 * C + ch + j] + ev[j];
      part = fmaf(q[j], kv[j], part);
    }
#pragma unroll
    for (int off = 32; off > 0; off >>= 1) part += __shfl_xor(part, off);
    float logit = part * scale;
    float nm = fmaxf(m, logit);
    float f = expf(m - nm);
    float w = expf(logit - nm);
    denom = denom * f + w;
#pragma unroll
    for (int j = 0; j < CPL; j++) acc[j] = acc[j] * f + w * vv[j];
    m = nm;
  }
  float inv = 1.f / (denom + 1e-16f);
#pragma unroll
  for (int j = 0; j < CPL; j++)
    h[(size_t)node * C + ch + j] = fmaxf(acc[j] * inv + skip[j], 0.f);
}

// ---- out[n] = h2[n] @ Wc + bc  (wave per node) ----
__global__ __launch_bounds__(256) void classifier_kernel(
    const float* __restrict__ h2, const float* __restrict__ Wc,
    const float* __restrict__ bc, float* __restrict__ out, int n) {
  int w = blockIdx.x * 4 + (threadIdx.x >> 6);
  int lane = threadIdx.x & 63;
  if (w >= n) return;
  float v = h2[(size_t)w * 64 + lane] * Wc[lane];
#pragma unroll
  for (int off = 32; off > 0; off >>= 1) v += __shfl_xor(v, off);
  if (lane == 0) out[w] = v + bc[0];
}

extern "C" void kernel_launch(void* const* d_in, const int* in_sizes, int n_in,
                              void* d_out, int out_size, void* d_ws,
                              size_t ws_size, hipStream_t stream) {
  const float* x         = (const float*)d_in[0];
  const int*   ei        = (const int*)d_in[1];
  const float* edge_attr = (const float*)d_in[2];
  const float* Wq1 = (const float*)d_in[3];  const float* bq1 = (const float*)d_in[4];
  const float* Wk1 = (const float*)d_in[5];  const float* bk1 = (const float*)d_in[6];
  const float* Wv1 = (const float*)d_in[7];  const float* bv1 = (const float*)d_in[8];
  const float* We1 = (const float*)d_in[9];
  const float* Ws1 = (const float*)d_in[10]; const float* bs1 = (const float*)d_in[11];
  const float* Wq2 = (const float*)d_in[12]; const float* bq2 = (const float*)d_in[13];
  const float* Wk2 = (const float*)d_in[14]; const float* bk2 = (const float*)d_in[15];
  const float* Wv2 = (const float*)d_in[16]; const float* bv2 = (const float*)d_in[17];
  const float* We2 = (const float*)d_in[18];
  const float* Ws2 = (const float*)d_in[19]; const float* bs2 = (const float*)d_in[20];
  const float* Wc  = (const float*)d_in[21]; const float* bc  = (const float*)d_in[22];
  float* out = (float*)d_out;

  const int* srcI = ei;        // edge_index[0]
  const int* dstI = ei + NE;   // edge_index[1]

  // ---- workspace layout (256B-aligned slices) ----
  char* ws = (char*)d_ws;
  size_t off = 0;
  auto alloc = [&](size_t bytes) {
    void* p = ws + off;
    off += (bytes + 255) & ~(size_t)255;
    return p;
  };
  float* P     = (float*)alloc((size_t)NN * 4 * H1 * 4);   // [N,512] L1 / [N,256] L2
  u16*   EwB   = (u16*)alloc((size_t)NE * EWS * 2);        // combined bf16 edge emb [E][192]
  float* h1    = (float*)alloc((size_t)NN * H1 * 4);
  float* h2    = (float*)alloc((size_t)NN * H2 * 4);
  u16* B1h = (u16*)alloc((size_t)4 * H1 * DIN * 2);
  u16* B1l = (u16*)alloc((size_t)4 * H1 * DIN * 2);
  u16* B2h = (u16*)alloc((size_t)4 * H2 * H1 * 2);
  u16* B2l = (u16*)alloc((size_t)4 * H2 * H1 * 2);
  u16* Ech = (u16*)alloc((size_t)EWS * DE * 2);            // [192][64] = [We1|We2]^T
  u16* Ecl = (u16*)alloc((size_t)EWS * DE * 2);
  float* b1cat = (float*)alloc(4 * H1 * 4);
  float* b2cat = (float*)alloc(4 * H2 * 4);
  int* deg       = (int*)alloc(NN * 4);
  int* cursor    = (int*)alloc(NN * 4);
  int* row_start = (int*)alloc((NN + 1) * 4);
  int* part      = (int*)alloc(((NN + 255) / 256) * 256 * 4);
  int* chunkSums = (int*)alloc(256 * 4);
  int* eid       = (int*)alloc(NE * 4);
  int* src_csr   = (int*)alloc(NE * 4);
  (void)ws_size; (void)in_sizes; (void)n_in; (void)out_size;

  const int nchunks = (NN + 255) / 256;  // 196 (<= 256)

  // ---- pack weights (transpose + bf16 split) ----
  packwt_kernel<<<256, 256, 0, stream>>>(Wq1, Wk1, Wv1, Ws1, bq1, bk1, bv1, bs1,
                                         B1h, B1l, b1cat, DIN, H1, 4);
  packwt_kernel<<<128, 256, 0, stream>>>(Wq2, Wk2, Wv2, Ws2, bq2, bk2, bv2, bs2,
                                         B2h, B2l, b2cat, H1, H2, 4);
  packwt_kernel<<<64, 256, 0, stream>>>(We1, nullptr, nullptr, nullptr, nullptr,
                                        nullptr, nullptr, nullptr, Ech, Ecl,
                                        nullptr, DE, H1, 1);
  packwt_kernel<<<32, 256, 0, stream>>>(We2, nullptr, nullptr, nullptr, nullptr,
                                        nullptr, nullptr, nullptr,
                                        Ech + (size_t)H1 * DE, Ecl + (size_t)H1 * DE,
                                        nullptr, DE, H2, 1);

  // ---- CSR build (sort edges by dst; deterministic within-node order) ----
  hipMemsetAsync(deg, 0, NN * sizeof(int), stream);
  hipMemsetAsync(cursor, 0, NN * sizeof(int), stream);
  hist_kernel<<<(NE + 255) / 256, 256, 0, stream>>>(dstI, deg, NE);
  scan1_kernel<<<nchunks, 256, 0, stream>>>(deg, part, chunkSums, NN);
  scan2_kernel<<<1, 256, 0, stream>>>(chunkSums, nchunks);
  scan3_kernel<<<nchunks, 256, 0, stream>>>(deg, part, chunkSums, row_start, NN, NE);
  scatter_kernel<<<(NE + 255) / 256, 256, 0, stream>>>(dstI, row_start, cursor,
                                                       eid, NE);
  sort_extract_kernel<<<(NN + 255) / 256, 256, 0, stream>>>(eid, row_start, srcI,
                                                            src_csr, NN);

  // ---- combined edge-embedding GEMM (both layers, bf16 output, CSR order) ----
  mfma_gemm_kernel<64, true><<<dim3(EWS / 64, NE / 128), 256, 0, stream>>>(
      edge_attr, eid, Ech, Ecl, nullptr, (float*)EwB, NE, EWS, DE);

  // ================= Layer 1 (C = H1 = 128) =================
  mfma_gemm_kernel<128, false><<<dim3(4 * H1 / 128, (NN + 127) / 128), 256, 0,
                                 stream>>>(x, nullptr, B1h, B1l, b1cat, P, NN,
                                           4 * H1, DIN);
  fused_edge_kernel<H1, 0><<<(NN + 3) / 4, 256, 0, stream>>>(
      P, EwB, row_start, src_csr, h1, 0.08838834764831845f, NN);

  // ================= Layer 2 (C = H2 = 64) =================
  mfma_gemm_kernel<128, false><<<dim3(4 * H2 / 128, (NN + 127) / 128), 256, 0,
                                 stream>>>(h1, nullptr, B2h, B2l, b2cat, P, NN,
                                           4 * H2, H1);
  fused_edge_kernel<H2, H1><<<(NN + 3) / 4, 256, 0, stream>>>(
      P, EwB, row_start, src_csr, h2, 0.125f, NN);

  // ================= Classifier =================
  classifier_kernel<<<(NN + 3) / 4, 256, 0, stream>>>(h2, Wc, bc, out, NN);
}

// Round 7
// 624.248 us; speedup vs baseline: 2.0778x; 1.0389x over previous
//
#include <hip/hip_runtime.h>
#include <math.h>

// Problem constants (match reference setup_inputs)
constexpr int NN  = 50000;   // nodes
constexpr int NE  = 640000;  // edges
constexpr int DIN = 256;
constexpr int DE  = 64;
constexpr int H1  = 128;
constexpr int H2  = 64;
constexpr int EWS = H1 + H2; // 192: combined edge-emb row stride

using u16 = unsigned short;
typedef __attribute__((ext_vector_type(8))) short bf16x8;
typedef __attribute__((ext_vector_type(4))) float f32x4;

// ---- fp32 -> bf16 (RTN) and back ----
__device__ inline u16 f2bf(float f) {
  unsigned u = __float_as_uint(f);
  unsigned r = (u + 0x7FFFu + ((u >> 16) & 1u)) >> 16;
  return (u16)r;
}
__device__ inline float bf2f(u16 h) { return __uint_as_float(((unsigned)h) << 16); }
__device__ inline unsigned pack2(u16 a, u16 b) {
  return (unsigned)a | ((unsigned)b << 16);
}
__device__ inline f32x4 mfma16(bf16x8 a, bf16x8 b, f32x4 c) {
  return __builtin_amdgcn_mfma_f32_16x16x32_bf16(a, b, c, 0, 0, 0);
}

// ---- pack nmats weight matrices W[K,C] into transposed split Bt[n][k] (n = which*C+cc)
__global__ __launch_bounds__(256) void packwt_kernel(
    const float* __restrict__ W0, const float* __restrict__ W1,
    const float* __restrict__ W2, const float* __restrict__ W3,
    const float* __restrict__ b0, const float* __restrict__ b1,
    const float* __restrict__ b2, const float* __restrict__ b3,
    u16* __restrict__ Bth, u16* __restrict__ Btl, float* __restrict__ bcat,
    int K, int C, int nmats) {
  int total = nmats * C * K;
  for (int idx = blockIdx.x * blockDim.x + threadIdx.x; idx < total;
       idx += gridDim.x * blockDim.x) {
    int k = idx % K;
    int n = idx / K;             // n = which*C + cc
    int which = n / C, cc = n % C;
    const float* W = which == 0 ? W0 : which == 1 ? W1 : which == 2 ? W2 : W3;
    float v = W[k * C + cc];
    u16 h = f2bf(v);
    Bth[(size_t)n * K + k] = h;
    Btl[(size_t)n * K + k] = f2bf(v - bf2f(h));
    if (k == 0 && bcat) {
      const float* b = which == 0 ? b0 : which == 1 ? b1 : which == 2 ? b2 : b3;
      bcat[n] = b ? b[cc] : 0.f;
    }
  }
}

// ---- CSR build ----
__global__ __launch_bounds__(256) void hist_kernel(const int* __restrict__ dst,
                                                   int* __restrict__ deg, int nE) {
  int e = blockIdx.x * blockDim.x + threadIdx.x;
  if (e < nE) atomicAdd(&deg[dst[e]], 1);
}

__global__ __launch_bounds__(256) void scan1_kernel(const int* __restrict__ deg,
                                                    int* __restrict__ part,
                                                    int* __restrict__ chunkSums,
                                                    int n) {
  __shared__ int s[256];
  int tid = threadIdx.x;
  int i = blockIdx.x * 256 + tid;
  int v0 = (i < n) ? deg[i] : 0;
  s[tid] = v0;
  __syncthreads();
  for (int off = 1; off < 256; off <<= 1) {
    int v = (tid >= off) ? s[tid - off] : 0;
    __syncthreads();
    s[tid] += v;
    __syncthreads();
  }
  if (i < n) part[i] = s[tid];
  if (tid == 255) chunkSums[blockIdx.x] = s[255];
}

__global__ __launch_bounds__(256) void scan2_kernel(int* __restrict__ chunkSums,
                                                    int nchunks) {
  __shared__ int s[256];
  int tid = threadIdx.x;
  s[tid] = (tid < nchunks) ? chunkSums[tid] : 0;
  __syncthreads();
  for (int off = 1; off < 256; off <<= 1) {
    int v = (tid >= off) ? s[tid - off] : 0;
    __syncthreads();
    s[tid] += v;
    __syncthreads();
  }
  if (tid < nchunks) chunkSums[tid] = s[tid];
}

__global__ __launch_bounds__(256) void scan3_kernel(const int* __restrict__ deg,
                                                    const int* __restrict__ part,
                                                    const int* __restrict__ chunkSums,
                                                    int* __restrict__ row_start,
                                                    int n, int nE) {
  int i = blockIdx.x * 256 + threadIdx.x;
  if (i < n)
    row_start[i] = part[i] - deg[i] + (blockIdx.x ? chunkSums[blockIdx.x - 1] : 0);
  if (i == 0) row_start[n] = nE;
}

__global__ __launch_bounds__(256) void scatter_kernel(const int* __restrict__ dst,
                                                      const int* __restrict__ row_start,
                                                      int* __restrict__ cursor,
                                                      int* __restrict__ eid, int nE) {
  int e = blockIdx.x * blockDim.x + threadIdx.x;
  if (e >= nE) return;
  int d = dst[e];
  int pos = row_start[d] + atomicAdd(&cursor[d], 1);
  eid[pos] = e;
}

__global__ __launch_bounds__(256) void sort_extract_kernel(
    int* __restrict__ eid, const int* __restrict__ row_start,
    const int* __restrict__ srcI, int* __restrict__ src_csr, int n) {
  int v = blockIdx.x * blockDim.x + threadIdx.x;
  if (v >= n) return;
  int b = row_start[v], e = row_start[v + 1];
  for (int i = b + 1; i < e; i++) {
    int key = eid[i];
    int j = i - 1;
    while (j >= b && eid[j] > key) { eid[j + 1] = eid[j]; j--; }
    eid[j + 1] = key;
  }
  for (int i = b; i < e; i++) src_csr[i] = srcI[eid[i]];
}

// ---- split-bf16 MFMA GEMM: out[M,Nn] = A[M,K](f32, optional row-gather) @ Bt^T + bias
// Bt pre-transposed split weights [Nn][K] (bf16 hi/lo). Nn % BN == 0, K % 32 == 0.
// EPI=0: fp32 -> Cout (stride Nn)
// EPI=1: bf16 -> (u16*)Cout (stride Nn), LDS-staged coalesced
// EPI=2: projection split: cols [0,Cl)->Qp f32, [Cl,3Cl)->KVp bf16 [M][2Cl], [3Cl,4Cl)->Sp f32
//        (requires BN <= Cl so each block hits exactly one segment)
template <int BN, int EPI>
__global__ __launch_bounds__(256) void mfma_gemm_kernel(
    const float* __restrict__ A, const int* __restrict__ ridx,
    const u16* __restrict__ Bth, const u16* __restrict__ Btl,
    const float* __restrict__ bias, float* __restrict__ Cout,
    float* __restrict__ Qp, u16* __restrict__ KVp, float* __restrict__ Sp,
    int M, int Nn, int K, int Cl) {
  constexpr int BM = 128, BK = 32;
  constexpr int NI = BN / 32;  // 16-col frags per wave (wave covers BN/2)
  __shared__ __align__(16) u16 smem[(BM + BN) * BK * 2];
  u16* Ah = smem;
  u16* Al = smem + BM * BK;
  u16* Bh = smem + 2 * BM * BK;
  u16* Bl = smem + 2 * BM * BK + BN * BK;
  int tid = threadIdx.x;
  int lane = tid & 63, wid = tid >> 6;
  int wm = wid >> 1, wn = wid & 1;
  int row0 = blockIdx.y * BM, col0 = blockIdx.x * BN;
  int k8 = lane >> 4, rb = lane & 15;

  f32x4 acc[4][NI];
#pragma unroll
  for (int mi = 0; mi < 4; mi++)
#pragma unroll
    for (int ni = 0; ni < NI; ni++) acc[mi][ni] = (f32x4){0.f, 0.f, 0.f, 0.f};

  // A staging assignments: 2 chunks (8 f32 each) per thread
  size_t aoff[2];
  int sdst[2];
  for (int p = 0; p < 2; p++) {
    int idx = p * 256 + tid;
    int r = idx >> 2, c = idx & 3;
    int ar = row0 + r;
    if (ar >= M) ar = M - 1;
    if (ridx) ar = ridx[ar];
    aoff[p] = (size_t)ar * K + c * 8;
    sdst[p] = r * BK + ((c ^ ((r >> 1) & 3)) << 3);  // chunk-XOR swizzle
  }

  for (int k0 = 0; k0 < K; k0 += BK) {
    __syncthreads();
    // stage A: read f32, split to bf16 hi/lo
#pragma unroll
    for (int p = 0; p < 2; p++) {
      const float* s = A + aoff[p] + k0;
      float4 u = *(const float4*)s, v = *(const float4*)(s + 4);
      float f[8] = {u.x, u.y, u.z, u.w, v.x, v.y, v.z, v.w};
      u16 h[8], l[8];
#pragma unroll
      for (int j = 0; j < 8; j++) {
        h[j] = f2bf(f[j]);
        l[j] = f2bf(f[j] - bf2f(h[j]));
      }
      *(uint4*)&Ah[sdst[p]] = make_uint4(pack2(h[0], h[1]), pack2(h[2], h[3]),
                                         pack2(h[4], h[5]), pack2(h[6], h[7]));
      *(uint4*)&Al[sdst[p]] = make_uint4(pack2(l[0], l[1]), pack2(l[2], l[3]),
                                         pack2(l[4], l[5]), pack2(l[6], l[7]));
    }
    // stage B (already bf16 split, [Nn][K] row-major)
#pragma unroll
    for (int p = 0; p < (BN * 4) / 256; p++) {
      int idx = p * 256 + tid;
      int n = idx >> 2, c = idx & 3;
      size_t goff = (size_t)(col0 + n) * K + k0 + c * 8;
      int doff = n * BK + ((c ^ ((n >> 1) & 3)) << 3);
      *(uint4*)&Bh[doff] = *(const uint4*)&Bth[goff];
      *(uint4*)&Bl[doff] = *(const uint4*)&Btl[goff];
    }
    __syncthreads();
    // fragments
    bf16x8 ah[4], al[4], bh[NI], bl[NI];
#pragma unroll
    for (int mi = 0; mi < 4; mi++) {
      int row = wm * 64 + mi * 16 + rb;
      int off = row * BK + ((k8 ^ ((row >> 1) & 3)) << 3);
      ah[mi] = *(const bf16x8*)&Ah[off];
      al[mi] = *(const bf16x8*)&Al[off];
    }
#pragma unroll
    for (int ni = 0; ni < NI; ni++) {
      int cn = wn * (BN / 2) + ni * 16 + rb;
      int off = cn * BK + ((k8 ^ ((cn >> 1) & 3)) << 3);
      bh[ni] = *(const bf16x8*)&Bh[off];
      bl[ni] = *(const bf16x8*)&Bl[off];
    }
#pragma unroll
    for (int mi = 0; mi < 4; mi++)
#pragma unroll
      for (int ni = 0; ni < NI; ni++) {
        f32x4 c = acc[mi][ni];
        c = mfma16(ah[mi], bh[ni], c);
        c = mfma16(al[mi], bh[ni], c);
        c = mfma16(ah[mi], bl[ni], c);
        acc[mi][ni] = c;
      }
  }

  // epilogue: D layout col=lane&15, row=(lane>>4)*4+reg (m89-verified)
  bool kvseg = false;
  if constexpr (EPI == 2) {
    int seg = col0 / Cl;
    kvseg = (seg == 1 || seg == 2);
    if (!kvseg) {
      float* dst = (seg == 0) ? Qp : Sp;
      int cbase = (seg == 0) ? col0 : col0 - 3 * Cl;
#pragma unroll
      for (int ni = 0; ni < NI; ni++) {
        int cfrag = wn * (BN / 2) + ni * 16 + rb;
        float bv = bias ? bias[col0 + cfrag] : 0.f;
#pragma unroll
        for (int mi = 0; mi < 4; mi++) {
#pragma unroll
          for (int q = 0; q < 4; q++) {
            int row = row0 + wm * 64 + mi * 16 + k8 * 4 + q;
            if (row < M)
              dst[(size_t)row * Cl + cbase + cfrag] = acc[mi][ni][q] + bv;
          }
        }
      }
      return;
    }
  }
  if (EPI == 1 || kvseg) {
    // stage bf16 tile in LDS (XOR-swizzled), then coalesced dwordx4 writes
    __syncthreads();
    u16* S = smem;  // [BM][BN] u16
#pragma unroll
    for (int ni = 0; ni < NI; ni++) {
      int coll = wn * (BN / 2) + ni * 16 + rb;
      float bv = bias ? bias[col0 + coll] : 0.f;
#pragma unroll
      for (int mi = 0; mi < 4; mi++) {
#pragma unroll
        for (int q = 0; q < 4; q++) {
          int rowl = wm * 64 + mi * 16 + k8 * 4 + q;
          S[rowl * BN + (coll ^ (((rowl >> 2) & 3) << 4))] =
              f2bf(acc[mi][ni][q] + bv);
        }
      }
    }
    __syncthreads();
    u16* dbase;
    size_t dstride;
    int dcol0;
    if constexpr (EPI == 2) {
      dbase = KVp; dstride = 2 * Cl; dcol0 = col0 - Cl;
    } else {
      dbase = (u16*)Cout; dstride = Nn; dcol0 = col0;
    }
    constexpr int PASSES = (BM * BN * 2) / (256 * 16);
#pragma unroll
    for (int p = 0; p < PASSES; p++) {
      int idx = p * 256 + tid;      // uint4 index
      int r = idx / (BN / 8);
      int cp = idx % (BN / 8);
      int row = row0 + r;
      int cps = cp ^ (((r >> 2) & 3) << 1);  // inverse of the <<4 u16 swizzle
      if (row < M)
        *(uint4*)&dbase[(size_t)row * dstride + dcol0 + cp * 8] =
            *(const uint4*)&S[r * BN + cps * 8];
    }
    return;
  }
  if constexpr (EPI == 0) {
#pragma unroll
    for (int ni = 0; ni < NI; ni++) {
      int col = col0 + wn * (BN / 2) + ni * 16 + rb;
      float bv = bias ? bias[col] : 0.f;
#pragma unroll
      for (int mi = 0; mi < 4; mi++) {
#pragma unroll
        for (int q = 0; q < 4; q++) {
          int row = row0 + wm * 64 + mi * 16 + k8 * 4 + q;
          if (row < M) Cout[(size_t)row * Nn + col] = acc[mi][ni][q] + bv;
        }
      }
    }
  }
}

// ---- fused edge pass: online softmax + message agg + skip + relu ----
// wave per dst node. Q/SKIP f32 [N][C]; KV bf16 [N][2C] = [k|v]; Ew bf16 [E][EWS].
template <int C, int EOFF>
__global__ __launch_bounds__(256) void fused_edge_kernel(
    const float* __restrict__ Q, const float* __restrict__ SKIP,
    const u16* __restrict__ KV, const u16* __restrict__ Ew,
    const int* __restrict__ row_start, const int* __restrict__ src_csr,
    float* __restrict__ h, float scale, int n) {
  constexpr int CPL = C / 64;  // channels per lane
  int node = blockIdx.x * 4 + (threadIdx.x >> 6);
  int lane = threadIdx.x & 63;
  if (node >= n) return;
  int ch = lane * CPL;
  float q[CPL], acc[CPL], skip[CPL];
#pragma unroll
  for (int j = 0; j < CPL; j++) {
    q[j] = Q[(size_t)node * C + ch + j];
    skip[j] = SKIP[(size_t)node * C + ch + j];
    acc[j] = 0.f;
  }
  float m = -INFINITY, denom = 0.f;
  int b = row_start[node], e = row_start[node + 1];
  for (int i = b; i < e; i++) {
    int s = src_csr[i];
    const u16* kvp = KV + (size_t)s * (2 * C);
    const u16* Ee = Ew + (size_t)i * EWS + EOFF;
    float kk[CPL], vv[CPL], ev[CPL];
    if constexpr (CPL == 2) {
      unsigned uk = *(const unsigned*)(kvp + ch);
      unsigned uv = *(const unsigned*)(kvp + C + ch);
      unsigned ue = *(const unsigned*)(Ee + ch);
      kk[0] = bf2f((u16)uk); kk[1] = bf2f((u16)(uk >> 16));
      vv[0] = bf2f((u16)uv); vv[1] = bf2f((u16)(uv >> 16));
      ev[0] = bf2f((u16)ue); ev[1] = bf2f((u16)(ue >> 16));
    } else {
      kk[0] = bf2f(kvp[ch]);
      vv[0] = bf2f(kvp[C + ch]);
      ev[0] = bf2f(Ee[ch]);
    }
    float part = 0.f;
#pragma unroll
    for (int j = 0; j < CPL; j++) {
      part = fmaf(q[j], kk[j] + ev[j], part);
    }
#pragma unroll
    for (int off = 32; off > 0; off >>= 1) part += __shfl_xor(part, off);
    float logit = part * scale;
    float nm = fmaxf(m, logit);
    float f = expf(m - nm);
    float w = expf(logit - nm);
    denom = denom * f + w;
#pragma unroll
    for (int j = 0; j < CPL; j++) acc[j] = acc[j] * f + w * (vv[j] + ev[j]);
    m = nm;
  }
  float inv = 1.f / (denom + 1e-16f);
#pragma unroll
  for (int j = 0; j < CPL; j++)
    h[(size_t)node * C + ch + j] = fmaxf(acc[j] * inv + skip[j], 0.f);
}

// ---- out[n] = h2[n] @ Wc + bc  (wave per node) ----
__global__ __launch_bounds__(256) void classifier_kernel(
    const float* __restrict__ h2, const float* __restrict__ Wc,
    const float* __restrict__ bc, float* __restrict__ out, int n) {
  int w = blockIdx.x * 4 + (threadIdx.x >> 6);
  int lane = threadIdx.x & 63;
  if (w >= n) return;
  float v = h2[(size_t)w * 64 + lane] * Wc[lane];
#pragma unroll
  for (int off = 32; off > 0; off >>= 1) v += __shfl_xor(v, off);
  if (lane == 0) out[w] = v + bc[0];
}

extern "C" void kernel_launch(void* const* d_in, const int* in_sizes, int n_in,
                              void* d_out, int out_size, void* d_ws,
                              size_t ws_size, hipStream_t stream) {
  const float* x         = (const float*)d_in[0];
  const int*   ei        = (const int*)d_in[1];
  const float* edge_attr = (const float*)d_in[2];
  const float* Wq1 = (const float*)d_in[3];  const float* bq1 = (const float*)d_in[4];
  const float* Wk1 = (const float*)d_in[5];  const float* bk1 = (const float*)d_in[6];
  const float* Wv1 = (const float*)d_in[7];  const float* bv1 = (const float*)d_in[8];
  const float* We1 = (const float*)d_in[9];
  const float* Ws1 = (const float*)d_in[10]; const float* bs1 = (const float*)d_in[11];
  const float* Wq2 = (const float*)d_in[12]; const float* bq2 = (const float*)d_in[13];
  const float* Wk2 = (const float*)d_in[14]; const float* bk2 = (const float*)d_in[15];
  const float* Wv2 = (const float*)d_in[16]; const float* bv2 = (const float*)d_in[17];
  const float* We2 = (const float*)d_in[18];
  const float* Ws2 = (const float*)d_in[19]; const float* bs2 = (const float*)d_in[20];
  const float* Wc  = (const float*)d_in[21]; const float* bc  = (const float*)d_in[22];
  float* out = (float*)d_out;

  const int* srcI = ei;        // edge_index[0]
  const int* dstI = ei + NE;   // edge_index[1]

  // ---- workspace layout (256B-aligned slices) ----
  char* ws = (char*)d_ws;
  size_t off = 0;
  auto alloc = [&](size_t bytes) {
    void* p = ws + off;
    off += (bytes + 255) & ~(size_t)255;
    return p;
  };
  u16*   EwB  = (u16*)alloc((size_t)NE * EWS * 2);    // combined bf16 edge emb [E][192]
  float* Q1   = (float*)alloc((size_t)NN * H1 * 4);
  float* S1   = (float*)alloc((size_t)NN * H1 * 4);
  u16*   KV1  = (u16*)alloc((size_t)NN * 2 * H1 * 2); // [N][k|v] bf16
  float* Q2   = (float*)alloc((size_t)NN * H2 * 4);
  float* S2   = (float*)alloc((size_t)NN * H2 * 4);
  u16*   KV2  = (u16*)alloc((size_t)NN * 2 * H2 * 2);
  float* h1   = (float*)alloc((size_t)NN * H1 * 4);
  float* h2   = (float*)alloc((size_t)NN * H2 * 4);
  u16* B1h = (u16*)alloc((size_t)4 * H1 * DIN * 2);
  u16* B1l = (u16*)alloc((size_t)4 * H1 * DIN * 2);
  u16* B2h = (u16*)alloc((size_t)4 * H2 * H1 * 2);
  u16* B2l = (u16*)alloc((size_t)4 * H2 * H1 * 2);
  u16* Ech = (u16*)alloc((size_t)EWS * DE * 2);       // [192][64] = [We1|We2]^T
  u16* Ecl = (u16*)alloc((size_t)EWS * DE * 2);
  float* b1cat = (float*)alloc(4 * H1 * 4);
  float* b2cat = (float*)alloc(4 * H2 * 4);
  int* deg       = (int*)alloc(NN * 4);
  int* cursor    = (int*)alloc(NN * 4);
  int* row_start = (int*)alloc((NN + 1) * 4);
  int* part      = (int*)alloc(((NN + 255) / 256) * 256 * 4);
  int* chunkSums = (int*)alloc(256 * 4);
  int* eid       = (int*)alloc(NE * 4);
  int* src_csr   = (int*)alloc(NE * 4);
  (void)ws_size; (void)in_sizes; (void)n_in; (void)out_size;

  const int nchunks = (NN + 255) / 256;  // 196 (<= 256)

  // ---- pack weights (transpose + bf16 split) ----
  packwt_kernel<<<256, 256, 0, stream>>>(Wq1, Wk1, Wv1, Ws1, bq1, bk1, bv1, bs1,
                                         B1h, B1l, b1cat, DIN, H1, 4);
  packwt_kernel<<<128, 256, 0, stream>>>(Wq2, Wk2, Wv2, Ws2, bq2, bk2, bv2, bs2,
                                         B2h, B2l, b2cat, H1, H2, 4);
  packwt_kernel<<<64, 256, 0, stream>>>(We1, nullptr, nullptr, nullptr, nullptr,
                                        nullptr, nullptr, nullptr, Ech, Ecl,
                                        nullptr, DE, H1, 1);
  packwt_kernel<<<32, 256, 0, stream>>>(We2, nullptr, nullptr, nullptr, nullptr,
                                        nullptr, nullptr, nullptr,
                                        Ech + (size_t)H1 * DE, Ecl + (size_t)H1 * DE,
                                        nullptr, DE, H2, 1);

  // ---- CSR build (sort edges by dst; deterministic within-node order) ----
  hipMemsetAsync(deg, 0, NN * sizeof(int), stream);
  hipMemsetAsync(cursor, 0, NN * sizeof(int), stream);
  hist_kernel<<<(NE + 255) / 256, 256, 0, stream>>>(dstI, deg, NE);
  scan1_kernel<<<nchunks, 256, 0, stream>>>(deg, part, chunkSums, NN);
  scan2_kernel<<<1, 256, 0, stream>>>(chunkSums, nchunks);
  scan3_kernel<<<nchunks, 256, 0, stream>>>(deg, part, chunkSums, row_start, NN, NE);
  scatter_kernel<<<(NE + 255) / 256, 256, 0, stream>>>(dstI, row_start, cursor,
                                                       eid, NE);
  sort_extract_kernel<<<(NN + 255) / 256, 256, 0, stream>>>(eid, row_start, srcI,
                                                            src_csr, NN);

  // ---- combined edge-embedding GEMM (both layers, bf16 output, CSR order) ----
  mfma_gemm_kernel<64, 1><<<dim3(EWS / 64, NE / 128), 256, 0, stream>>>(
      edge_attr, eid, Ech, Ecl, nullptr, (float*)EwB,
      nullptr, nullptr, nullptr, NE, EWS, DE, 0);

  // ================= Layer 1 (C = H1 = 128) =================
  mfma_gemm_kernel<64, 2><<<dim3(4 * H1 / 64, (NN + 127) / 128), 256, 0, stream>>>(
      x, nullptr, B1h, B1l, b1cat, nullptr, Q1, KV1, S1, NN, 4 * H1, DIN, H1);
  fused_edge_kernel<H1, 0><<<(NN + 3) / 4, 256, 0, stream>>>(
      Q1, S1, KV1, EwB, row_start, src_csr, h1, 0.08838834764831845f, NN);

  // ================= Layer 2 (C = H2 = 64) =================
  mfma_gemm_kernel<64, 2><<<dim3(4 * H2 / 64, (NN + 127) / 128), 256, 0, stream>>>(
      h1, nullptr, B2h, B2l, b2cat, nullptr, Q2, KV2, S2, NN, 4 * H2, H1, H2);
  fused_edge_kernel<H2, H1><<<(NN + 3) / 4, 256, 0, stream>>>(
      Q2, S2, KV2, EwB, row_start, src_csr, h2, 0.125f, NN);

  // ================= Classifier =================
  classifier_kernel<<<(NN + 3) / 4, 256, 0, stream>>>(h2, Wc, bc, out, NN);
}

// Round 8
// 548.421 us; speedup vs baseline: 2.3651x; 1.1383x over previous
//
#include <hip/hip_runtime.h>
#include <math.h>

// Problem constants (match reference setup_inputs)
constexpr int NN  = 50000;   // nodes
constexpr int NE  = 640000;  // edges
constexpr int DIN = 256;
constexpr int DE  = 64;
constexpr int H1  = 128;
constexpr int H2  = 64;
constexpr int EWS = H1 + H2; // 192: combined edge-emb row stride

using u16 = unsigned short;
typedef __attribute__((ext_vector_type(8))) short bf16x8;
typedef __attribute__((ext_vector_type(4))) float f32x4;

// ---- fp32 -> bf16 (RTN) and back ----
__device__ inline u16 f2bf(float f) {
  unsigned u = __float_as_uint(f);
  unsigned r = (u + 0x7FFFu + ((u >> 16) & 1u)) >> 16;
  return (u16)r;
}
__device__ inline float bf2f(u16 h) { return __uint_as_float(((unsigned)h) << 16); }
__device__ inline unsigned pack2(u16 a, u16 b) {
  return (unsigned)a | ((unsigned)b << 16);
}
__device__ inline f32x4 mfma16(bf16x8 a, bf16x8 b, f32x4 c) {
  return __builtin_amdgcn_mfma_f32_16x16x32_bf16(a, b, c, 0, 0, 0);
}

// ---- pack nmats weight matrices W[K,C] into transposed split Bt[n][k] (n = which*C+cc)
__global__ __launch_bounds__(256) void packwt_kernel(
    const float* __restrict__ W0, const float* __restrict__ W1,
    const float* __restrict__ W2, const float* __restrict__ W3,
    const float* __restrict__ b0, const float* __restrict__ b1,
    const float* __restrict__ b2, const float* __restrict__ b3,
    u16* __restrict__ Bth, u16* __restrict__ Btl, float* __restrict__ bcat,
    int K, int C, int nmats) {
  int total = nmats * C * K;
  for (int idx = blockIdx.x * blockDim.x + threadIdx.x; idx < total;
       idx += gridDim.x * blockDim.x) {
    int k = idx % K;
    int n = idx / K;             // n = which*C + cc
    int which = n / C, cc = n % C;
    const float* W = which == 0 ? W0 : which == 1 ? W1 : which == 2 ? W2 : W3;
    float v = W[k * C + cc];
    u16 h = f2bf(v);
    Bth[(size_t)n * K + k] = h;
    Btl[(size_t)n * K + k] = f2bf(v - bf2f(h));
    if (k == 0 && bcat) {
      const float* b = which == 0 ? b0 : which == 1 ? b1 : which == 2 ? b2 : b3;
      bcat[n] = b ? b[cc] : 0.f;
    }
  }
}

// ---- CSR build ----
__global__ __launch_bounds__(256) void hist_kernel(const int* __restrict__ dst,
                                                   int* __restrict__ deg, int nE) {
  int e = blockIdx.x * blockDim.x + threadIdx.x;
  if (e < nE) atomicAdd(&deg[dst[e]], 1);
}

__global__ __launch_bounds__(256) void scan1_kernel(const int* __restrict__ deg,
                                                    int* __restrict__ part,
                                                    int* __restrict__ chunkSums,
                                                    int n) {
  __shared__ int s[256];
  int tid = threadIdx.x;
  int i = blockIdx.x * 256 + tid;
  int v0 = (i < n) ? deg[i] : 0;
  s[tid] = v0;
  __syncthreads();
  for (int off = 1; off < 256; off <<= 1) {
    int v = (tid >= off) ? s[tid - off] : 0;
    __syncthreads();
    s[tid] += v;
    __syncthreads();
  }
  if (i < n) part[i] = s[tid];
  if (tid == 255) chunkSums[blockIdx.x] = s[255];
}

__global__ __launch_bounds__(256) void scan2_kernel(int* __restrict__ chunkSums,
                                                    int nchunks) {
  __shared__ int s[256];
  int tid = threadIdx.x;
  s[tid] = (tid < nchunks) ? chunkSums[tid] : 0;
  __syncthreads();
  for (int off = 1; off < 256; off <<= 1) {
    int v = (tid >= off) ? s[tid - off] : 0;
    __syncthreads();
    s[tid] += v;
    __syncthreads();
  }
  if (tid < nchunks) chunkSums[tid] = s[tid];
}

__global__ __launch_bounds__(256) void scan3_kernel(const int* __restrict__ deg,
                                                    const int* __restrict__ part,
                                                    const int* __restrict__ chunkSums,
                                                    int* __restrict__ row_start,
                                                    int n, int nE) {
  int i = blockIdx.x * 256 + threadIdx.x;
  if (i < n)
    row_start[i] = part[i] - deg[i] + (blockIdx.x ? chunkSums[blockIdx.x - 1] : 0);
  if (i == 0) row_start[n] = nE;
}

__global__ __launch_bounds__(256) void scatter_kernel(const int* __restrict__ dst,
                                                      const int* __restrict__ row_start,
                                                      int* __restrict__ cursor,
                                                      int* __restrict__ eid, int nE) {
  int e = blockIdx.x * blockDim.x + threadIdx.x;
  if (e >= nE) return;
  int d = dst[e];
  int pos = row_start[d] + atomicAdd(&cursor[d], 1);
  eid[pos] = e;
}

__global__ __launch_bounds__(256) void sort_extract_kernel(
    int* __restrict__ eid, const int* __restrict__ row_start,
    const int* __restrict__ srcI, int* __restrict__ src_csr, int n) {
  int v = blockIdx.x * blockDim.x + threadIdx.x;
  if (v >= n) return;
  int b = row_start[v], e = row_start[v + 1];
  for (int i = b + 1; i < e; i++) {
    int key = eid[i];
    int j = i - 1;
    while (j >= b && eid[j] > key) { eid[j + 1] = eid[j]; j--; }
    eid[j + 1] = key;
  }
  for (int i = b; i < e; i++) src_csr[i] = srcI[eid[i]];
}

// ---- split-bf16 MFMA GEMM: out[M,Nn] = A[M,K](f32, optional row-gather) @ Bt^T + bias
// Bt pre-transposed split weights [Nn][K] (bf16 hi/lo). Nn % BN == 0, K % 32 == 0.
// EPI=0: fp32 -> Cout (stride Nn)
// EPI=1: bf16 -> (u16*)Cout (stride Nn), LDS-staged coalesced
// EPI=2: projection split: cols [0,Cl)->Qp f32, [Cl,3Cl)->KVp bf16 [M][2Cl], [3Cl,4Cl)->Sp f32
//        (requires BN <= Cl so each block hits exactly one segment)
template <int BN, int EPI>
__global__ __launch_bounds__(256) void mfma_gemm_kernel(
    const float* __restrict__ A, const int* __restrict__ ridx,
    const u16* __restrict__ Bth, const u16* __restrict__ Btl,
    const float* __restrict__ bias, float* __restrict__ Cout,
    float* __restrict__ Qp, u16* __restrict__ KVp, float* __restrict__ Sp,
    int M, int Nn, int K, int Cl) {
  constexpr int BM = 128, BK = 32;
  constexpr int NI = BN / 32;  // 16-col frags per wave (wave covers BN/2)
  constexpr int SM_STAGE = (BM + BN) * BK * 2;
  constexpr int SM_EPI = (EPI >= 1) ? BM * BN : 0;
  constexpr int SM = SM_STAGE > SM_EPI ? SM_STAGE : SM_EPI;
  __shared__ __align__(16) u16 smem[SM];
  u16* Ah = smem;
  u16* Al = smem + BM * BK;
  u16* Bh = smem + 2 * BM * BK;
  u16* Bl = smem + 2 * BM * BK + BN * BK;
  int tid = threadIdx.x;
  int lane = tid & 63, wid = tid >> 6;
  int wm = wid >> 1, wn = wid & 1;
  int row0 = blockIdx.y * BM, col0 = blockIdx.x * BN;
  int k8 = lane >> 4, rb = lane & 15;

  f32x4 acc[4][NI];
#pragma unroll
  for (int mi = 0; mi < 4; mi++)
#pragma unroll
    for (int ni = 0; ni < NI; ni++) acc[mi][ni] = (f32x4){0.f, 0.f, 0.f, 0.f};

  // A staging assignments: 2 chunks (8 f32 each) per thread
  size_t aoff[2];
  int sdst[2];
  for (int p = 0; p < 2; p++) {
    int idx = p * 256 + tid;
    int r = idx >> 2, c = idx & 3;
    int ar = row0 + r;
    if (ar >= M) ar = M - 1;
    if (ridx) ar = ridx[ar];
    aoff[p] = (size_t)ar * K + c * 8;
    sdst[p] = r * BK + ((c ^ ((r >> 1) & 3)) << 3);  // chunk-XOR swizzle
  }

  for (int k0 = 0; k0 < K; k0 += BK) {
    __syncthreads();
    // stage A: read f32, split to bf16 hi/lo
#pragma unroll
    for (int p = 0; p < 2; p++) {
      const float* s = A + aoff[p] + k0;
      float4 u = *(const float4*)s, v = *(const float4*)(s + 4);
      float f[8] = {u.x, u.y, u.z, u.w, v.x, v.y, v.z, v.w};
      u16 h[8], l[8];
#pragma unroll
      for (int j = 0; j < 8; j++) {
        h[j] = f2bf(f[j]);
        l[j] = f2bf(f[j] - bf2f(h[j]));
      }
      *(uint4*)&Ah[sdst[p]] = make_uint4(pack2(h[0], h[1]), pack2(h[2], h[3]),
                                         pack2(h[4], h[5]), pack2(h[6], h[7]));
      *(uint4*)&Al[sdst[p]] = make_uint4(pack2(l[0], l[1]), pack2(l[2], l[3]),
                                         pack2(l[4], l[5]), pack2(l[6], l[7]));
    }
    // stage B (already bf16 split, [Nn][K] row-major)
#pragma unroll
    for (int p = 0; p < (BN * 4) / 256; p++) {
      int idx = p * 256 + tid;
      int n = idx >> 2, c = idx & 3;
      size_t goff = (size_t)(col0 + n) * K + k0 + c * 8;
      int doff = n * BK + ((c ^ ((n >> 1) & 3)) << 3);
      *(uint4*)&Bh[doff] = *(const uint4*)&Bth[goff];
      *(uint4*)&Bl[doff] = *(const uint4*)&Btl[goff];
    }
    __syncthreads();
    // fragments
    bf16x8 ah[4], al[4], bh[NI], bl[NI];
#pragma unroll
    for (int mi = 0; mi < 4; mi++) {
      int row = wm * 64 + mi * 16 + rb;
      int off = row * BK + ((k8 ^ ((row >> 1) & 3)) << 3);
      ah[mi] = *(const bf16x8*)&Ah[off];
      al[mi] = *(const bf16x8*)&Al[off];
    }
#pragma unroll
    for (int ni = 0; ni < NI; ni++) {
      int cn = wn * (BN / 2) + ni * 16 + rb;
      int off = cn * BK + ((k8 ^ ((cn >> 1) & 3)) << 3);
      bh[ni] = *(const bf16x8*)&Bh[off];
      bl[ni] = *(const bf16x8*)&Bl[off];
    }
#pragma unroll
    for (int mi = 0; mi < 4; mi++)
#pragma unroll
      for (int ni = 0; ni < NI; ni++) {
        f32x4 c = acc[mi][ni];
        c = mfma16(ah[mi], bh[ni], c);
        c = mfma16(al[mi], bh[ni], c);
        c = mfma16(ah[mi], bl[ni], c);
        acc[mi][ni] = c;
      }
  }

  // epilogue: D layout col=lane&15, row=(lane>>4)*4+reg (m89-verified)
  bool kvseg = false;
  if constexpr (EPI == 2) {
    int seg = col0 / Cl;
    kvseg = (seg == 1 || seg == 2);
    if (!kvseg) {
      float* dst = (seg == 0) ? Qp : Sp;
      int cbase = (seg == 0) ? col0 : col0 - 3 * Cl;
#pragma unroll
      for (int ni = 0; ni < NI; ni++) {
        int cfrag = wn * (BN / 2) + ni * 16 + rb;
        float bv = bias ? bias[col0 + cfrag] : 0.f;
#pragma unroll
        for (int mi = 0; mi < 4; mi++) {
#pragma unroll
          for (int q = 0; q < 4; q++) {
            int row = row0 + wm * 64 + mi * 16 + k8 * 4 + q;
            if (row < M)
              dst[(size_t)row * Cl + cbase + cfrag] = acc[mi][ni][q] + bv;
          }
        }
      }
      return;
    }
  }
  if (EPI == 1 || kvseg) {
    // stage bf16 tile in LDS (XOR-swizzled), then coalesced dwordx4 writes
    __syncthreads();
    u16* S = smem;  // [BM][BN] u16
#pragma unroll
    for (int ni = 0; ni < NI; ni++) {
      int coll = wn * (BN / 2) + ni * 16 + rb;
      float bv = bias ? bias[col0 + coll] : 0.f;
#pragma unroll
      for (int mi = 0; mi < 4; mi++) {
#pragma unroll
        for (int q = 0; q < 4; q++) {
          int rowl = wm * 64 + mi * 16 + k8 * 4 + q;
          S[rowl * BN + (coll ^ (((rowl >> 2) & 3) << 4))] =
              f2bf(acc[mi][ni][q] + bv);
        }
      }
    }
    __syncthreads();
    u16* dbase;
    size_t dstride;
    int dcol0;
    if constexpr (EPI == 2) {
      dbase = KVp; dstride = 2 * Cl; dcol0 = col0 - Cl;
    } else {
      dbase = (u16*)Cout; dstride = Nn; dcol0 = col0;
    }
    constexpr int PASSES = (BM * BN * 2) / (256 * 16);
#pragma unroll
    for (int p = 0; p < PASSES; p++) {
      int idx = p * 256 + tid;      // uint4 index
      int r = idx / (BN / 8);
      int cp = idx % (BN / 8);
      int row = row0 + r;
      int cps = cp ^ (((r >> 2) & 3) << 1);  // inverse of the <<4 u16 swizzle
      if (row < M)
        *(uint4*)&dbase[(size_t)row * dstride + dcol0 + cp * 8] =
            *(const uint4*)&S[r * BN + cps * 8];
    }
    return;
  }
  if constexpr (EPI == 0) {
#pragma unroll
    for (int ni = 0; ni < NI; ni++) {
      int col = col0 + wn * (BN / 2) + ni * 16 + rb;
      float bv = bias ? bias[col] : 0.f;
#pragma unroll
      for (int mi = 0; mi < 4; mi++) {
#pragma unroll
        for (int q = 0; q < 4; q++) {
          int row = row0 + wm * 64 + mi * 16 + k8 * 4 + q;
          if (row < M) Cout[(size_t)row * Nn + col] = acc[mi][ni][q] + bv;
        }
      }
    }
  }
}

// ---- fused edge pass: 4-edge-batched online softmax + message agg + skip + relu
// wave per dst node. Q/SKIP f32 [N][C]; KV bf16 [N][2C] = [k|v]; Ew bf16 [E][EWS].
// 4 edges/iteration: independent gathers + 4 parallel shuffle-reduce trees (ILP
// hides ds_bpermute latency), one online-softmax rescale per batch.
template <int C, int EOFF>
__global__ __launch_bounds__(256) void fused_edge_kernel(
    const float* __restrict__ Q, const float* __restrict__ SKIP,
    const u16* __restrict__ KV, const u16* __restrict__ Ew,
    const int* __restrict__ row_start, const int* __restrict__ src_csr,
    float* __restrict__ h, float scale, int n) {
  constexpr int CPL = C / 64;  // channels per lane
  int node = blockIdx.x * 4 + (threadIdx.x >> 6);
  int lane = threadIdx.x & 63;
  if (node >= n) return;
  int ch = lane * CPL;
  float q[CPL], acc[CPL], skip[CPL];
#pragma unroll
  for (int j = 0; j < CPL; j++) {
    q[j] = Q[(size_t)node * C + ch + j];
    skip[j] = SKIP[(size_t)node * C + ch + j];
    acc[j] = 0.f;
  }
  float m = -INFINITY, denom = 0.f;
  int b = row_start[node], e = row_start[node + 1];
  for (int i = b; i < e; i += 4) {
    float part[4], vv[4][CPL];
#pragma unroll
    for (int u = 0; u < 4; u++) {
      int idx = (i + u < e) ? i + u : e - 1;  // tail: clamp loads, zeroed by w=0
      int s = src_csr[idx];
      const u16* kvp = KV + (size_t)s * (2 * C);
      const u16* Ee = Ew + (size_t)idx * EWS + EOFF;
      float kk[CPL], ev[CPL];
      if constexpr (CPL == 2) {
        unsigned uk = *(const unsigned*)(kvp + ch);
        unsigned uv = *(const unsigned*)(kvp + C + ch);
        unsigned ue = *(const unsigned*)(Ee + ch);
        kk[0] = bf2f((u16)uk); kk[1] = bf2f((u16)(uk >> 16));
        vv[u][0] = bf2f((u16)uv); vv[u][1] = bf2f((u16)(uv >> 16));
        ev[0] = bf2f((u16)ue); ev[1] = bf2f((u16)(ue >> 16));
      } else {
        kk[0] = bf2f(kvp[ch]);
        vv[u][0] = bf2f(kvp[C + ch]);
        ev[0] = bf2f(Ee[ch]);
      }
      float p = 0.f;
#pragma unroll
      for (int j = 0; j < CPL; j++) {
        p = fmaf(q[j], kk[j] + ev[j], p);
        vv[u][j] += ev[j];
      }
      part[u] = p;
    }
    // 4 independent butterfly reductions (ILP across trees)
#pragma unroll
    for (int off = 32; off > 0; off >>= 1) {
      part[0] += __shfl_xor(part[0], off);
      part[1] += __shfl_xor(part[1], off);
      part[2] += __shfl_xor(part[2], off);
      part[3] += __shfl_xor(part[3], off);
    }
    float l[4];
#pragma unroll
    for (int u = 0; u < 4; u++)
      l[u] = (i + u < e) ? part[u] * scale : -INFINITY;
    float nm = fmaxf(fmaxf(fmaxf(l[0], l[1]), fmaxf(l[2], l[3])), m);
    float f = expf(m - nm);  // 0 on first batch (m = -inf)
    float w[4];
#pragma unroll
    for (int u = 0; u < 4; u++) w[u] = expf(l[u] - nm);  // -inf -> 0
    denom = denom * f + (w[0] + w[1]) + (w[2] + w[3]);
#pragma unroll
    for (int j = 0; j < CPL; j++) {
      float a = acc[j] * f;
      a = fmaf(w[0], vv[0][j], a);
      a = fmaf(w[1], vv[1][j], a);
      a = fmaf(w[2], vv[2][j], a);
      a = fmaf(w[3], vv[3][j], a);
      acc[j] = a;
    }
    m = nm;
  }
  float inv = 1.f / (denom + 1e-16f);
#pragma unroll
  for (int j = 0; j < CPL; j++)
    h[(size_t)node * C + ch + j] = fmaxf(acc[j] * inv + skip[j], 0.f);
}

// ---- out[n] = h2[n] @ Wc + bc  (wave per node) ----
__global__ __launch_bounds__(256) void classifier_kernel(
    const float* __restrict__ h2, const float* __restrict__ Wc,
    const float* __restrict__ bc, float* __restrict__ out, int n) {
  int w = blockIdx.x * 4 + (threadIdx.x >> 6);
  int lane = threadIdx.x & 63;
  if (w >= n) return;
  float v = h2[(size_t)w * 64 + lane] * Wc[lane];
#pragma unroll
  for (int off = 32; off > 0; off >>= 1) v += __shfl_xor(v, off);
  if (lane == 0) out[w] = v + bc[0];
}

extern "C" void kernel_launch(void* const* d_in, const int* in_sizes, int n_in,
                              void* d_out, int out_size, void* d_ws,
                              size_t ws_size, hipStream_t stream) {
  const float* x         = (const float*)d_in[0];
  const int*   ei        = (const int*)d_in[1];
  const float* edge_attr = (const float*)d_in[2];
  const float* Wq1 = (const float*)d_in[3];  const float* bq1 = (const float*)d_in[4];
  const float* Wk1 = (const float*)d_in[5];  const float* bk1 = (const float*)d_in[6];
  const float* Wv1 = (const float*)d_in[7];  const float* bv1 = (const float*)d_in[8];
  const float* We1 = (const float*)d_in[9];
  const float* Ws1 = (const float*)d_in[10]; const float* bs1 = (const float*)d_in[11];
  const float* Wq2 = (const float*)d_in[12]; const float* bq2 = (const float*)d_in[13];
  const float* Wk2 = (const float*)d_in[14]; const float* bk2 = (const float*)d_in[15];
  const float* Wv2 = (const float*)d_in[16]; const float* bv2 = (const float*)d_in[17];
  const float* We2 = (const float*)d_in[18];
  const float* Ws2 = (const float*)d_in[19]; const float* bs2 = (const float*)d_in[20];
  const float* Wc  = (const float*)d_in[21]; const float* bc  = (const float*)d_in[22];
  float* out = (float*)d_out;

  const int* srcI = ei;        // edge_index[0]
  const int* dstI = ei + NE;   // edge_index[1]

  // ---- workspace layout (256B-aligned slices) ----
  char* ws = (char*)d_ws;
  size_t off = 0;
  auto alloc = [&](size_t bytes) {
    void* p = ws + off;
    off += (bytes + 255) & ~(size_t)255;
    return p;
  };
  u16*   EwB  = (u16*)alloc((size_t)NE * EWS * 2);    // combined bf16 edge emb [E][192]
  float* Q1   = (float*)alloc((size_t)NN * H1 * 4);
  float* S1   = (float*)alloc((size_t)NN * H1 * 4);
  u16*   KV1  = (u16*)alloc((size_t)NN * 2 * H1 * 2); // [N][k|v] bf16
  float* Q2   = (float*)alloc((size_t)NN * H2 * 4);
  float* S2   = (float*)alloc((size_t)NN * H2 * 4);
  u16*   KV2  = (u16*)alloc((size_t)NN * 2 * H2 * 2);
  float* h1   = (float*)alloc((size_t)NN * H1 * 4);
  float* h2   = (float*)alloc((size_t)NN * H2 * 4);
  u16* B1h = (u16*)alloc((size_t)4 * H1 * DIN * 2);
  u16* B1l = (u16*)alloc((size_t)4 * H1 * DIN * 2);
  u16* B2h = (u16*)alloc((size_t)4 * H2 * H1 * 2);
  u16* B2l = (u16*)alloc((size_t)4 * H2 * H1 * 2);
  u16* Ech = (u16*)alloc((size_t)EWS * DE * 2);       // [192][64] = [We1|We2]^T
  u16* Ecl = (u16*)alloc((size_t)EWS * DE * 2);
  float* b1cat = (float*)alloc(4 * H1 * 4);
  float* b2cat = (float*)alloc(4 * H2 * 4);
  int* deg       = (int*)alloc(NN * 4);
  int* cursor    = (int*)alloc(NN * 4);
  int* row_start = (int*)alloc((NN + 1) * 4);
  int* part      = (int*)alloc(((NN + 255) / 256) * 256 * 4);
  int* chunkSums = (int*)alloc(256 * 4);
  int* eid       = (int*)alloc(NE * 4);
  int* src_csr   = (int*)alloc(NE * 4);
  (void)ws_size; (void)in_sizes; (void)n_in; (void)out_size;

  const int nchunks = (NN + 255) / 256;  // 196 (<= 256)

  // ---- pack weights (transpose + bf16 split) ----
  packwt_kernel<<<256, 256, 0, stream>>>(Wq1, Wk1, Wv1, Ws1, bq1, bk1, bv1, bs1,
                                         B1h, B1l, b1cat, DIN, H1, 4);
  packwt_kernel<<<128, 256, 0, stream>>>(Wq2, Wk2, Wv2, Ws2, bq2, bk2, bv2, bs2,
                                         B2h, B2l, b2cat, H1, H2, 4);
  packwt_kernel<<<64, 256, 0, stream>>>(We1, nullptr, nullptr, nullptr, nullptr,
                                        nullptr, nullptr, nullptr, Ech, Ecl,
                                        nullptr, DE, H1, 1);
  packwt_kernel<<<32, 256, 0, stream>>>(We2, nullptr, nullptr, nullptr, nullptr,
                                        nullptr, nullptr, nullptr,
                                        Ech + (size_t)H1 * DE, Ecl + (size_t)H1 * DE,
                                        nullptr, DE, H2, 1);

  // ---- CSR build (sort edges by dst; deterministic within-node order) ----
  hipMemsetAsync(deg, 0, NN * sizeof(int), stream);
  hipMemsetAsync(cursor, 0, NN * sizeof(int), stream);
  hist_kernel<<<(NE + 255) / 256, 256, 0, stream>>>(dstI, deg, NE);
  scan1_kernel<<<nchunks, 256, 0, stream>>>(deg, part, chunkSums, NN);
  scan2_kernel<<<1, 256, 0, stream>>>(chunkSums, nchunks);
  scan3_kernel<<<nchunks, 256, 0, stream>>>(deg, part, chunkSums, row_start, NN, NE);
  scatter_kernel<<<(NE + 255) / 256, 256, 0, stream>>>(dstI, row_start, cursor,
                                                       eid, NE);
  sort_extract_kernel<<<(NN + 255) / 256, 256, 0, stream>>>(eid, row_start, srcI,
                                                            src_csr, NN);

  // ---- combined edge-embedding GEMM (both layers, bf16 out, CSR order) ----
  // BN=192: single column-block so each gathered edge_attr row is staged once.
  mfma_gemm_kernel<192, 1><<<dim3(1, NE / 128), 256, 0, stream>>>(
      edge_attr, eid, Ech, Ecl, nullptr, (float*)EwB,
      nullptr, nullptr, nullptr, NE, EWS, DE, 0);

  // ================= Layer 1 (C = H1 = 128) =================
  mfma_gemm_kernel<64, 2><<<dim3(4 * H1 / 64, (NN + 127) / 128), 256, 0, stream>>>(
      x, nullptr, B1h, B1l, b1cat, nullptr, Q1, KV1, S1, NN, 4 * H1, DIN, H1);
  fused_edge_kernel<H1, 0><<<(NN + 3) / 4, 256, 0, stream>>>(
      Q1, S1, KV1, EwB, row_start, src_csr, h1, 0.08838834764831845f, NN);

  // ================= Layer 2 (C = H2 = 64) =================
  mfma_gemm_kernel<64, 2><<<dim3(4 * H2 / 64, (NN + 127) / 128), 256, 0, stream>>>(
      h1, nullptr, B2h, B2l, b2cat, nullptr, Q2, KV2, S2, NN, 4 * H2, H1, H2);
  fused_edge_kernel<H2, H1><<<(NN + 3) / 4, 256, 0, stream>>>(
      Q2, S2, KV2, EwB, row_start, src_csr, h2, 0.125f, NN);

  // ================= Classifier =================
  classifier_kernel<<<(NN + 3) / 4, 256, 0, stream>>>(h2, Wc, bc, out, NN);
}

// Round 9
// 505.741 us; speedup vs baseline: 2.5646x; 1.0844x over previous
//
#include <hip/hip_runtime.h>
#include <math.h>

// Problem constants (match reference setup_inputs)
constexpr int NN  = 50000;   // nodes
constexpr int NE  = 640000;  // edges
constexpr int DIN = 256;
constexpr int DE  = 64;
constexpr int H1  = 128;
constexpr int H2  = 64;
constexpr int EWS = H1 + H2; // 192: combined edge-emb row stride

using u16 = unsigned short;
typedef __attribute__((ext_vector_type(8))) short bf16x8;
typedef __attribute__((ext_vector_type(4))) float f32x4;

// ---- fp32 -> bf16 (RTN) and back ----
__device__ inline u16 f2bf(float f) {
  unsigned u = __float_as_uint(f);
  unsigned r = (u + 0x7FFFu + ((u >> 16) & 1u)) >> 16;
  return (u16)r;
}
__device__ inline float bf2f(u16 h) { return __uint_as_float(((unsigned)h) << 16); }
__device__ inline unsigned pack2(u16 a, u16 b) {
  return (unsigned)a | ((unsigned)b << 16);
}
__device__ inline f32x4 mfma16(bf16x8 a, bf16x8 b, f32x4 c) {
  return __builtin_amdgcn_mfma_f32_16x16x32_bf16(a, b, c, 0, 0, 0);
}

// ---- pack nmats weight matrices W[K,C] into transposed split Bt[n][k] (n = which*C+cc)
__global__ __launch_bounds__(256) void packwt_kernel(
    const float* __restrict__ W0, const float* __restrict__ W1,
    const float* __restrict__ W2, const float* __restrict__ W3,
    const float* __restrict__ b0, const float* __restrict__ b1,
    const float* __restrict__ b2, const float* __restrict__ b3,
    u16* __restrict__ Bth, u16* __restrict__ Btl, float* __restrict__ bcat,
    int K, int C, int nmats) {
  int total = nmats * C * K;
  for (int idx = blockIdx.x * blockDim.x + threadIdx.x; idx < total;
       idx += gridDim.x * blockDim.x) {
    int k = idx % K;
    int n = idx / K;             // n = which*C + cc
    int which = n / C, cc = n % C;
    const float* W = which == 0 ? W0 : which == 1 ? W1 : which == 2 ? W2 : W3;
    float v = W[k * C + cc];
    u16 h = f2bf(v);
    Bth[(size_t)n * K + k] = h;
    Btl[(size_t)n * K + k] = f2bf(v - bf2f(h));
    if (k == 0 && bcat) {
      const float* b = which == 0 ? b0 : which == 1 ? b1 : which == 2 ? b2 : b3;
      bcat[n] = b ? b[cc] : 0.f;
    }
  }
}

// ---- CSR build ----
__global__ __launch_bounds__(256) void hist_kernel(const int* __restrict__ dst,
                                                   int* __restrict__ deg, int nE) {
  int e = blockIdx.x * blockDim.x + threadIdx.x;
  if (e < nE) atomicAdd(&deg[dst[e]], 1);
}

__global__ __launch_bounds__(256) void scan1_kernel(const int* __restrict__ deg,
                                                    int* __restrict__ part,
                                                    int* __restrict__ chunkSums,
                                                    int n) {
  __shared__ int s[256];
  int tid = threadIdx.x;
  int i = blockIdx.x * 256 + tid;
  int v0 = (i < n) ? deg[i] : 0;
  s[tid] = v0;
  __syncthreads();
  for (int off = 1; off < 256; off <<= 1) {
    int v = (tid >= off) ? s[tid - off] : 0;
    __syncthreads();
    s[tid] += v;
    __syncthreads();
  }
  if (i < n) part[i] = s[tid];
  if (tid == 255) chunkSums[blockIdx.x] = s[255];
}

__global__ __launch_bounds__(256) void scan2_kernel(int* __restrict__ chunkSums,
                                                    int nchunks) {
  __shared__ int s[256];
  int tid = threadIdx.x;
  s[tid] = (tid < nchunks) ? chunkSums[tid] : 0;
  __syncthreads();
  for (int off = 1; off < 256; off <<= 1) {
    int v = (tid >= off) ? s[tid - off] : 0;
    __syncthreads();
    s[tid] += v;
    __syncthreads();
  }
  if (tid < nchunks) chunkSums[tid] = s[tid];
}

__global__ __launch_bounds__(256) void scan3_kernel(const int* __restrict__ deg,
                                                    const int* __restrict__ part,
                                                    const int* __restrict__ chunkSums,
                                                    int* __restrict__ row_start,
                                                    int n, int nE) {
  int i = blockIdx.x * 256 + threadIdx.x;
  if (i < n)
    row_start[i] = part[i] - deg[i] + (blockIdx.x ? chunkSums[blockIdx.x - 1] : 0);
  if (i == 0) row_start[n] = nE;
}

__global__ __launch_bounds__(256) void scatter_kernel(const int* __restrict__ dst,
                                                      const int* __restrict__ row_start,
                                                      int* __restrict__ cursor,
                                                      int* __restrict__ eid, int nE) {
  int e = blockIdx.x * blockDim.x + threadIdx.x;
  if (e >= nE) return;
  int d = dst[e];
  int pos = row_start[d] + atomicAdd(&cursor[d], 1);
  eid[pos] = e;
}

__global__ __launch_bounds__(256) void sort_extract_kernel(
    int* __restrict__ eid, const int* __restrict__ row_start,
    const int* __restrict__ srcI, int* __restrict__ src_csr, int n) {
  int v = blockIdx.x * blockDim.x + threadIdx.x;
  if (v >= n) return;
  int b = row_start[v], e = row_start[v + 1];
  for (int i = b + 1; i < e; i++) {
    int key = eid[i];
    int j = i - 1;
    while (j >= b && eid[j] > key) { eid[j + 1] = eid[j]; j--; }
    eid[j + 1] = key;
  }
  for (int i = b; i < e; i++) src_csr[i] = srcI[eid[i]];
}

// ---- split-bf16 MFMA GEMM (generic, BM=128, 256 thr):
// out[M,Nn] = A[M,K](f32, optional row-gather) @ Bt^T + bias
// EPI=0: fp32 -> Cout (stride Nn)
// EPI=2: projection split: cols [0,Cl)->Qp f32, [Cl,3Cl)->KVp bf16 [M][2Cl], [3Cl,4Cl)->Sp f32
//        (requires BN <= Cl so each block hits exactly one segment)
template <int BN, int EPI>
__global__ __launch_bounds__(256) void mfma_gemm_kernel(
    const float* __restrict__ A, const int* __restrict__ ridx,
    const u16* __restrict__ Bth, const u16* __restrict__ Btl,
    const float* __restrict__ bias, float* __restrict__ Cout,
    float* __restrict__ Qp, u16* __restrict__ KVp, float* __restrict__ Sp,
    int M, int Nn, int K, int Cl) {
  constexpr int BM = 128, BK = 32;
  constexpr int NI = BN / 32;  // 16-col frags per wave (wave covers BN/2)
  constexpr int SM_STAGE = (BM + BN) * BK * 2;
  constexpr int SM_EPI = (EPI >= 1) ? BM * BN : 0;
  constexpr int SM = SM_STAGE > SM_EPI ? SM_STAGE : SM_EPI;
  __shared__ __align__(16) u16 smem[SM];
  u16* Ah = smem;
  u16* Al = smem + BM * BK;
  u16* Bh = smem + 2 * BM * BK;
  u16* Bl = smem + 2 * BM * BK + BN * BK;
  int tid = threadIdx.x;
  int lane = tid & 63, wid = tid >> 6;
  int wm = wid >> 1, wn = wid & 1;
  int row0 = blockIdx.y * BM, col0 = blockIdx.x * BN;
  int k8 = lane >> 4, rb = lane & 15;

  f32x4 acc[4][NI];
#pragma unroll
  for (int mi = 0; mi < 4; mi++)
#pragma unroll
    for (int ni = 0; ni < NI; ni++) acc[mi][ni] = (f32x4){0.f, 0.f, 0.f, 0.f};

  // A staging assignments: 2 chunks (8 f32 each) per thread
  size_t aoff[2];
  int sdst[2];
  for (int p = 0; p < 2; p++) {
    int idx = p * 256 + tid;
    int r = idx >> 2, c = idx & 3;
    int ar = row0 + r;
    if (ar >= M) ar = M - 1;
    if (ridx) ar = ridx[ar];
    aoff[p] = (size_t)ar * K + c * 8;
    sdst[p] = r * BK + ((c ^ ((r >> 1) & 3)) << 3);  // chunk-XOR swizzle
  }

  for (int k0 = 0; k0 < K; k0 += BK) {
    __syncthreads();
    // stage A: read f32, split to bf16 hi/lo
#pragma unroll
    for (int p = 0; p < 2; p++) {
      const float* s = A + aoff[p] + k0;
      float4 u = *(const float4*)s, v = *(const float4*)(s + 4);
      float f[8] = {u.x, u.y, u.z, u.w, v.x, v.y, v.z, v.w};
      u16 h[8], l[8];
#pragma unroll
      for (int j = 0; j < 8; j++) {
        h[j] = f2bf(f[j]);
        l[j] = f2bf(f[j] - bf2f(h[j]));
      }
      *(uint4*)&Ah[sdst[p]] = make_uint4(pack2(h[0], h[1]), pack2(h[2], h[3]),
                                         pack2(h[4], h[5]), pack2(h[6], h[7]));
      *(uint4*)&Al[sdst[p]] = make_uint4(pack2(l[0], l[1]), pack2(l[2], l[3]),
                                         pack2(l[4], l[5]), pack2(l[6], l[7]));
    }
    // stage B (already bf16 split, [Nn][K] row-major)
#pragma unroll
    for (int p = 0; p < (BN * 4) / 256; p++) {
      int idx = p * 256 + tid;
      int n = idx >> 2, c = idx & 3;
      size_t goff = (size_t)(col0 + n) * K + k0 + c * 8;
      int doff = n * BK + ((c ^ ((n >> 1) & 3)) << 3);
      *(uint4*)&Bh[doff] = *(const uint4*)&Bth[goff];
      *(uint4*)&Bl[doff] = *(const uint4*)&Btl[goff];
    }
    __syncthreads();
    // fragments
    bf16x8 ah[4], al[4], bh[NI], bl[NI];
#pragma unroll
    for (int mi = 0; mi < 4; mi++) {
      int row = wm * 64 + mi * 16 + rb;
      int off = row * BK + ((k8 ^ ((row >> 1) & 3)) << 3);
      ah[mi] = *(const bf16x8*)&Ah[off];
      al[mi] = *(const bf16x8*)&Al[off];
    }
#pragma unroll
    for (int ni = 0; ni < NI; ni++) {
      int cn = wn * (BN / 2) + ni * 16 + rb;
      int off = cn * BK + ((k8 ^ ((cn >> 1) & 3)) << 3);
      bh[ni] = *(const bf16x8*)&Bh[off];
      bl[ni] = *(const bf16x8*)&Bl[off];
    }
#pragma unroll
    for (int mi = 0; mi < 4; mi++)
#pragma unroll
      for (int ni = 0; ni < NI; ni++) {
        f32x4 c = acc[mi][ni];
        c = mfma16(ah[mi], bh[ni], c);
        c = mfma16(al[mi], bh[ni], c);
        c = mfma16(ah[mi], bl[ni], c);
        acc[mi][ni] = c;
      }
  }

  // epilogue: D layout col=lane&15, row=(lane>>4)*4+reg (m89-verified)
  bool kvseg = false;
  if constexpr (EPI == 2) {
    int seg = col0 / Cl;
    kvseg = (seg == 1 || seg == 2);
    if (!kvseg) {
      float* dst = (seg == 0) ? Qp : Sp;
      int cbase = (seg == 0) ? col0 : col0 - 3 * Cl;
#pragma unroll
      for (int ni = 0; ni < NI; ni++) {
        int cfrag = wn * (BN / 2) + ni * 16 + rb;
        float bv = bias ? bias[col0 + cfrag] : 0.f;
#pragma unroll
        for (int mi = 0; mi < 4; mi++) {
#pragma unroll
          for (int q = 0; q < 4; q++) {
            int row = row0 + wm * 64 + mi * 16 + k8 * 4 + q;
            if (row < M)
              dst[(size_t)row * Cl + cbase + cfrag] = acc[mi][ni][q] + bv;
          }
        }
      }
      return;
    }
  }
  if (kvseg) {
    // stage bf16 tile in LDS (XOR-swizzled), then coalesced dwordx4 writes
    __syncthreads();
    u16* S = smem;  // [BM][BN] u16
#pragma unroll
    for (int ni = 0; ni < NI; ni++) {
      int coll = wn * (BN / 2) + ni * 16 + rb;
      float bv = bias ? bias[col0 + coll] : 0.f;
#pragma unroll
      for (int mi = 0; mi < 4; mi++) {
#pragma unroll
        for (int q = 0; q < 4; q++) {
          int rowl = wm * 64 + mi * 16 + k8 * 4 + q;
          S[rowl * BN + (coll ^ (((rowl >> 2) & 3) << 4))] =
              f2bf(acc[mi][ni][q] + bv);
        }
      }
    }
    __syncthreads();
    u16* dbase = KVp;
    size_t dstride = 2 * Cl;
    int dcol0 = col0 - Cl;
    constexpr int PASSES = (BM * BN * 2) / (256 * 16);
#pragma unroll
    for (int p = 0; p < PASSES; p++) {
      int idx = p * 256 + tid;      // uint4 index
      int r = idx / (BN / 8);
      int cp = idx % (BN / 8);
      int row = row0 + r;
      int cps = cp ^ (((r >> 2) & 3) << 1);  // inverse of the <<4 u16 swizzle
      if (row < M)
        *(uint4*)&dbase[(size_t)row * dstride + dcol0 + cp * 8] =
            *(const uint4*)&S[r * BN + cps * 8];
    }
    return;
  }
  if constexpr (EPI == 0) {
#pragma unroll
    for (int ni = 0; ni < NI; ni++) {
      int col = col0 + wn * (BN / 2) + ni * 16 + rb;
      float bv = bias ? bias[col] : 0.f;
#pragma unroll
      for (int mi = 0; mi < 4; mi++) {
#pragma unroll
        for (int q = 0; q < 4; q++) {
          int row = row0 + wm * 64 + mi * 16 + k8 * 4 + q;
          if (row < M) Cout[(size_t)row * Nn + col] = acc[mi][ni][q] + bv;
        }
      }
    }
  }
}

// ---- dedicated edge-embedding GEMM: EwB[NE][192] bf16 = edge_attr[eid] @ Ec^T
// BM=256 x BN=192, 8 waves (512 thr), K=64. 2 blocks/CU; epilogue in 2 halves.
__global__ __launch_bounds__(512) void edge_gemm_kernel(
    const float* __restrict__ A, const int* __restrict__ ridx,
    const u16* __restrict__ Bth, const u16* __restrict__ Btl,
    u16* __restrict__ Cbf) {
  constexpr int BM = 256, BN = 192, BK = 32, K = DE;  // K = 64
  constexpr int NI = 6;  // wave covers 96 cols
  __shared__ __align__(16) u16 smem[(BM + BN) * BK * 2];  // 57344 B
  u16* Ah = smem;
  u16* Al = smem + BM * BK;
  u16* Bh = smem + 2 * BM * BK;
  u16* Bl = smem + 2 * BM * BK + BN * BK;
  int tid = threadIdx.x;
  int lane = tid & 63, wid = tid >> 6;
  int wm = wid >> 1, wn = wid & 1;          // wm: 4 row-strips of 64, wn: 2 col-halves
  int row0 = blockIdx.x * BM;
  int k8 = lane >> 4, rb = lane & 15;

  f32x4 acc[4][NI];
#pragma unroll
  for (int mi = 0; mi < 4; mi++)
#pragma unroll
    for (int ni = 0; ni < NI; ni++) acc[mi][ni] = (f32x4){0.f, 0.f, 0.f, 0.f};

  // A staging: 1024 chunk-tasks / 512 thr = 2 per thread
  size_t aoff[2];
  int sdst[2];
#pragma unroll
  for (int p = 0; p < 2; p++) {
    int idx = p * 512 + tid;
    int r = idx >> 2, c = idx & 3;
    int ar = ridx[row0 + r];
    aoff[p] = (size_t)ar * K + c * 8;
    sdst[p] = r * BK + ((c ^ ((r >> 1) & 3)) << 3);
  }

  for (int k0 = 0; k0 < K; k0 += BK) {
    __syncthreads();
#pragma unroll
    for (int p = 0; p < 2; p++) {
      const float* s = A + aoff[p] + k0;
      float4 u = *(const float4*)s, v = *(const float4*)(s + 4);
      float f[8] = {u.x, u.y, u.z, u.w, v.x, v.y, v.z, v.w};
      u16 h[8], l[8];
#pragma unroll
      for (int j = 0; j < 8; j++) {
        h[j] = f2bf(f[j]);
        l[j] = f2bf(f[j] - bf2f(h[j]));
      }
      *(uint4*)&Ah[sdst[p]] = make_uint4(pack2(h[0], h[1]), pack2(h[2], h[3]),
                                         pack2(h[4], h[5]), pack2(h[6], h[7]));
      *(uint4*)&Al[sdst[p]] = make_uint4(pack2(l[0], l[1]), pack2(l[2], l[3]),
                                         pack2(l[4], l[5]), pack2(l[6], l[7]));
    }
    // B staging: 768 tasks, 2 passes with bounds check
#pragma unroll
    for (int p = 0; p < 2; p++) {
      int idx = p * 512 + tid;
      if (idx < BN * 4) {
        int n = idx >> 2, c = idx & 3;
        size_t goff = (size_t)n * K + k0 + c * 8;
        int doff = n * BK + ((c ^ ((n >> 1) & 3)) << 3);
        *(uint4*)&Bh[doff] = *(const uint4*)&Bth[goff];
        *(uint4*)&Bl[doff] = *(const uint4*)&Btl[goff];
      }
    }
    __syncthreads();
    bf16x8 ah[4], al[4], bh[NI], bl[NI];
#pragma unroll
    for (int mi = 0; mi < 4; mi++) {
      int row = wm * 64 + mi * 16 + rb;
      int off = row * BK + ((k8 ^ ((row >> 1) & 3)) << 3);
      ah[mi] = *(const bf16x8*)&Ah[off];
      al[mi] = *(const bf16x8*)&Al[off];
    }
#pragma unroll
    for (int ni = 0; ni < NI; ni++) {
      int cn = wn * 96 + ni * 16 + rb;
      int off = cn * BK + ((k8 ^ ((cn >> 1) & 3)) << 3);
      bh[ni] = *(const bf16x8*)&Bh[off];
      bl[ni] = *(const bf16x8*)&Bl[off];
    }
#pragma unroll
    for (int mi = 0; mi < 4; mi++)
#pragma unroll
      for (int ni = 0; ni < NI; ni++) {
        f32x4 c = acc[mi][ni];
        c = mfma16(ah[mi], bh[ni], c);
        c = mfma16(al[mi], bh[ni], c);
        c = mfma16(ah[mi], bl[ni], c);
        acc[mi][ni] = c;
      }
  }

  // epilogue: two 128-row halves through LDS (S = 128*192 u16 = 24576 <= 28672)
  u16* S = smem;
#pragma unroll
  for (int half = 0; half < 2; half++) {
    __syncthreads();
    if ((wm >> 1) == half) {
#pragma unroll
      for (int ni = 0; ni < NI; ni++) {
        int coll = wn * 96 + ni * 16 + rb;
#pragma unroll
        for (int mi = 0; mi < 4; mi++) {
#pragma unroll
          for (int q = 0; q < 4; q++) {
            int rowl = (wm & 1) * 64 + mi * 16 + k8 * 4 + q;
            S[rowl * BN + (coll ^ (((rowl >> 2) & 3) << 4))] =
                f2bf(acc[mi][ni][q]);
          }
        }
      }
    }
    __syncthreads();
    // 128 rows x 24 uint4 = 3072 / 512 thr = 6 passes; rows contiguous in global
#pragma unroll
    for (int p = 0; p < 6; p++) {
      int idx = p * 512 + tid;
      int r = idx / (BN / 8);
      int cp = idx % (BN / 8);
      int row = row0 + half * 128 + r;
      int cps = cp ^ (((r >> 2) & 3) << 1);
      *(uint4*)&Cbf[(size_t)row * BN + cp * 8] = *(const uint4*)&S[r * BN + cps * 8];
    }
  }
}

// ---- fused edge pass: 4-edge-batched online softmax + message agg + skip + relu
template <int C, int EOFF>
__global__ __launch_bounds__(256) void fused_edge_kernel(
    const float* __restrict__ Q, const float* __restrict__ SKIP,
    const u16* __restrict__ KV, const u16* __restrict__ Ew,
    const int* __restrict__ row_start, const int* __restrict__ src_csr,
    float* __restrict__ h, float scale, int n) {
  constexpr int CPL = C / 64;  // channels per lane
  int node = blockIdx.x * 4 + (threadIdx.x >> 6);
  int lane = threadIdx.x & 63;
  if (node >= n) return;
  int ch = lane * CPL;
  float q[CPL], acc[CPL], skip[CPL];
#pragma unroll
  for (int j = 0; j < CPL; j++) {
    q[j] = Q[(size_t)node * C + ch + j];
    skip[j] = SKIP[(size_t)node * C + ch + j];
    acc[j] = 0.f;
  }
  float m = -INFINITY, denom = 0.f;
  int b = row_start[node], e = row_start[node + 1];
  for (int i = b; i < e; i += 4) {
    float part[4], vv[4][CPL];
#pragma unroll
    for (int u = 0; u < 4; u++) {
      int idx = (i + u < e) ? i + u : e - 1;  // tail: clamp loads, zeroed by w=0
      int s = src_csr[idx];
      const u16* kvp = KV + (size_t)s * (2 * C);
      const u16* Ee = Ew + (size_t)idx * EWS + EOFF;
      float kk[CPL], ev[CPL];
      if constexpr (CPL == 2) {
        unsigned uk = *(const unsigned*)(kvp + ch);
        unsigned uv = *(const unsigned*)(kvp + C + ch);
        unsigned ue = *(const unsigned*)(Ee + ch);
        kk[0] = bf2f((u16)uk); kk[1] = bf2f((u16)(uk >> 16));
        vv[u][0] = bf2f((u16)uv); vv[u][1] = bf2f((u16)(uv >> 16));
        ev[0] = bf2f((u16)ue); ev[1] = bf2f((u16)(ue >> 16));
      } else {
        kk[0] = bf2f(kvp[ch]);
        vv[u][0] = bf2f(kvp[C + ch]);
        ev[0] = bf2f(Ee[ch]);
      }
      float p = 0.f;
#pragma unroll
      for (int j = 0; j < CPL; j++) {
        p = fmaf(q[j], kk[j] + ev[j], p);
        vv[u][j] += ev[j];
      }
      part[u] = p;
    }
    // 4 independent butterfly reductions (ILP across trees)
#pragma unroll
    for (int off = 32; off > 0; off >>= 1) {
      part[0] += __shfl_xor(part[0], off);
      part[1] += __shfl_xor(part[1], off);
      part[2] += __shfl_xor(part[2], off);
      part[3] += __shfl_xor(part[3], off);
    }
    float l[4];
#pragma unroll
    for (int u = 0; u < 4; u++)
      l[u] = (i + u < e) ? part[u] * scale : -INFINITY;
    float nm = fmaxf(fmaxf(fmaxf(l[0], l[1]), fmaxf(l[2], l[3])), m);
    float f = expf(m - nm);  // 0 on first batch (m = -inf)
    float w[4];
#pragma unroll
    for (int u = 0; u < 4; u++) w[u] = expf(l[u] - nm);  // -inf -> 0
    denom = denom * f + (w[0] + w[1]) + (w[2] + w[3]);
#pragma unroll
    for (int j = 0; j < CPL; j++) {
      float a = acc[j] * f;
      a = fmaf(w[0], vv[0][j], a);
      a = fmaf(w[1], vv[1][j], a);
      a = fmaf(w[2], vv[2][j], a);
      a = fmaf(w[3], vv[3][j], a);
      acc[j] = a;
    }
    m = nm;
  }
  float inv = 1.f / (denom + 1e-16f);
#pragma unroll
  for (int j = 0; j < CPL; j++)
    h[(size_t)node * C + ch + j] = fmaxf(acc[j] * inv + skip[j], 0.f);
}

// ---- out[n] = h2[n] @ Wc + bc  (wave per node) ----
__global__ __launch_bounds__(256) void classifier_kernel(
    const float* __restrict__ h2, const float* __restrict__ Wc,
    const float* __restrict__ bc, float* __restrict__ out, int n) {
  int w = blockIdx.x * 4 + (threadIdx.x >> 6);
  int lane = threadIdx.x & 63;
  if (w >= n) return;
  float v = h2[(size_t)w * 64 + lane] * Wc[lane];
#pragma unroll
  for (int off = 32; off > 0; off >>= 1) v += __shfl_xor(v, off);
  if (lane == 0) out[w] = v + bc[0];
}

extern "C" void kernel_launch(void* const* d_in, const int* in_sizes, int n_in,
                              void* d_out, int out_size, void* d_ws,
                              size_t ws_size, hipStream_t stream) {
  const float* x         = (const float*)d_in[0];
  const int*   ei        = (const int*)d_in[1];
  const float* edge_attr = (const float*)d_in[2];
  const float* Wq1 = (const float*)d_in[3];  const float* bq1 = (const float*)d_in[4];
  const float* Wk1 = (const float*)d_in[5];  const float* bk1 = (const float*)d_in[6];
  const float* Wv1 = (const float*)d_in[7];  const float* bv1 = (const float*)d_in[8];
  const float* We1 = (const float*)d_in[9];
  const float* Ws1 = (const float*)d_in[10]; const float* bs1 = (const float*)d_in[11];
  const float* Wq2 = (const float*)d_in[12]; const float* bq2 = (const float*)d_in[13];
  const float* Wk2 = (const float*)d_in[14]; const float* bk2 = (const float*)d_in[15];
  const float* Wv2 = (const float*)d_in[16]; const float* bv2 = (const float*)d_in[17];
  const float* We2 = (const float*)d_in[18];
  const float* Ws2 = (const float*)d_in[19]; const float* bs2 = (const float*)d_in[20];
  const float* Wc  = (const float*)d_in[21]; const float* bc  = (const float*)d_in[22];
  float* out = (float*)d_out;

  const int* srcI = ei;        // edge_index[0]
  const int* dstI = ei + NE;   // edge_index[1]

  // ---- workspace layout (256B-aligned slices) ----
  char* ws = (char*)d_ws;
  size_t off = 0;
  auto alloc = [&](size_t bytes) {
    void* p = ws + off;
    off += (bytes + 255) & ~(size_t)255;
    return p;
  };
  u16*   EwB  = (u16*)alloc((size_t)NE * EWS * 2);    // combined bf16 edge emb [E][192]
  float* Q1   = (float*)alloc((size_t)NN * H1 * 4);
  float* S1   = (float*)alloc((size_t)NN * H1 * 4);
  u16*   KV1  = (u16*)alloc((size_t)NN * 2 * H1 * 2); // [N][k|v] bf16
  float* Q2   = (float*)alloc((size_t)NN * H2 * 4);
  float* S2   = (float*)alloc((size_t)NN * H2 * 4);
  u16*   KV2  = (u16*)alloc((size_t)NN * 2 * H2 * 2);
  float* h1   = (float*)alloc((size_t)NN * H1 * 4);
  float* h2   = (float*)alloc((size_t)NN * H2 * 4);
  u16* B1h = (u16*)alloc((size_t)4 * H1 * DIN * 2);
  u16* B1l = (u16*)alloc((size_t)4 * H1 * DIN * 2);
  u16* B2h = (u16*)alloc((size_t)4 * H2 * H1 * 2);
  u16* B2l = (u16*)alloc((size_t)4 * H2 * H1 * 2);
  u16* Ech = (u16*)alloc((size_t)EWS * DE * 2);       // [192][64] = [We1|We2]^T
  u16* Ecl = (u16*)alloc((size_t)EWS * DE * 2);
  float* b1cat = (float*)alloc(4 * H1 * 4);
  float* b2cat = (float*)alloc(4 * H2 * 4);
  int* deg       = (int*)alloc(NN * 4);
  int* cursor    = (int*)alloc(NN * 4);
  int* row_start = (int*)alloc((NN + 1) * 4);
  int* part      = (int*)alloc(((NN + 255) / 256) * 256 * 4);
  int* chunkSums = (int*)alloc(256 * 4);
  int* eid       = (int*)alloc(NE * 4);
  int* src_csr   = (int*)alloc(NE * 4);
  (void)ws_size; (void)in_sizes; (void)n_in; (void)out_size;

  const int nchunks = (NN + 255) / 256;  // 196 (<= 256)

  // ---- pack weights (transpose + bf16 split) ----
  packwt_kernel<<<256, 256, 0, stream>>>(Wq1, Wk1, Wv1, Ws1, bq1, bk1, bv1, bs1,
                                         B1h, B1l, b1cat, DIN, H1, 4);
  packwt_kernel<<<128, 256, 0, stream>>>(Wq2, Wk2, Wv2, Ws2, bq2, bk2, bv2, bs2,
                                         B2h, B2l, b2cat, H1, H2, 4);
  packwt_kernel<<<64, 256, 0, stream>>>(We1, nullptr, nullptr, nullptr, nullptr,
                                        nullptr, nullptr, nullptr, Ech, Ecl,
                                        nullptr, DE, H1, 1);
  packwt_kernel<<<32, 256, 0, stream>>>(We2, nullptr, nullptr, nullptr, nullptr,
                                        nullptr, nullptr, nullptr,
                                        Ech + (size_t)H1 * DE, Ecl + (size_t)H1 * DE,
                                        nullptr, DE, H2, 1);

  // ---- CSR build (sort edges by dst; deterministic within-node order) ----
  hipMemsetAsync(deg, 0, NN * sizeof(int), stream);
  hipMemsetAsync(cursor, 0, NN * sizeof(int), stream);
  hist_kernel<<<(NE + 255) / 256, 256, 0, stream>>>(dstI, deg, NE);
  scan1_kernel<<<nchunks, 256, 0, stream>>>(deg, part, chunkSums, NN);
  scan2_kernel<<<1, 256, 0, stream>>>(chunkSums, nchunks);
  scan3_kernel<<<nchunks, 256, 0, stream>>>(deg, part, chunkSums, row_start, NN, NE);
  scatter_kernel<<<(NE + 255) / 256, 256, 0, stream>>>(dstI, row_start, cursor,
                                                       eid, NE);
  sort_extract_kernel<<<(NN + 255) / 256, 256, 0, stream>>>(eid, row_start, srcI,
                                                            src_csr, NN);

  // ---- combined edge-embedding GEMM (both layers, bf16 out, CSR order) ----
  edge_gemm_kernel<<<NE / 256, 512, 0, stream>>>(edge_attr, eid, Ech, Ecl, EwB);

  // ================= Layer 1 (C = H1 = 128) =================
  mfma_gemm_kernel<128, 2><<<dim3(4 * H1 / 128, (NN + 127) / 128), 256, 0, stream>>>(
      x, nullptr, B1h, B1l, b1cat, nullptr, Q1, KV1, S1, NN, 4 * H1, DIN, H1);
  fused_edge_kernel<H1, 0><<<(NN + 3) / 4, 256, 0, stream>>>(
      Q1, S1, KV1, EwB, row_start, src_csr, h1, 0.08838834764831845f, NN);

  // ================= Layer 2 (C = H2 = 64) =================
  mfma_gemm_kernel<64, 2><<<dim3(4 * H2 / 64, (NN + 127) / 128), 256, 0, stream>>>(
      h1, nullptr, B2h, B2l, b2cat, nullptr, Q2, KV2, S2, NN, 4 * H2, H1, H2);
  fused_edge_kernel<H2, H1><<<(NN + 3) / 4, 256, 0, stream>>>(
      Q2, S2, KV2, EwB, row_start, src_csr, h2, 0.125f, NN);

  // ================= Classifier =================
  classifier_kernel<<<(NN + 3) / 4, 256, 0, stream>>>(h2, Wc, bc, out, NN);
}